// Round 12
// baseline (457.416 us; speedup 1.0000x reference)
//
#include <hip/hip_runtime.h>
#include <hip/hip_bf16.h>
#include <math.h>

// Problem constants
#define BB 8
#define SS 2048
#define TT (BB * SS)      // 16384 tokens
#define DM 256
#define DI 512
#define DSTATE 16
#define DCONV 4
#define NLAYERS 2
#define VOCAB 256
#define LOG_VOCAB 5.545177444479562f
#define RMS_EPS 1.1920929e-07f
#define LOG2E 1.4426950408889634f
#define LN2 0.6931471805599453f
#define THR_ 0.5f

#define TW 16            // tokens per fused block: grid 1024, 37.9KB LDS -> 4 blocks/CU
#define XBST 264         // xbs (A-tile) LDS row stride (bf16): 528B -> 2-way aliasing only
#define XST 520          // xcs LDS row stride (bf16 elems): 1040B -> 2-way bank aliasing only
#define BMST 20          // Bms LDS row stride (f32)
#define VST 260          // vst (f32 epilogue overlay) row stride; 16*260*4=16640 <= xbs 16896
#define HST3 264         // hts (head A-tile) row stride (bf16)
#define HTS_OFF 20480    // hts: inside dead xcs region (xcs starts 16896, ends 36656)
#define RED_OFF 36656    // red: reuses Bms region (dead after P2b); 1024B <= 1280B

typedef __attribute__((ext_vector_type(8))) __bf16 bf16x8;
typedef __attribute__((ext_vector_type(4))) __bf16 bf16x4;
typedef __attribute__((ext_vector_type(2))) __bf16 bf16x2;
typedef __attribute__((ext_vector_type(4))) float f32x4;

// ---- fast transcendentals (1-ulp class; entropy margin vs THR=0.5 is ~0.4) ----
__device__ __forceinline__ float fexp(float x) { return __builtin_amdgcn_exp2f(x * LOG2E); }
__device__ __forceinline__ float fexp2(float x) { return __builtin_amdgcn_exp2f(x); }
__device__ __forceinline__ float flog(float x) { return __builtin_amdgcn_logf(x) * LN2; }
__device__ __forceinline__ float frcp(float x) { return __builtin_amdgcn_rcpf(x); }
__device__ __forceinline__ float fsigmoid(float x) { return frcp(1.f + fexp(-x)); }
__device__ __forceinline__ float fsoftplus(float x) {
  return fmaxf(x, 0.f) + flog(1.f + fexp(-fabsf(x)));
}

// ---------------------------------------------------------------------------
// prep_wtrans: merged weight transposes (bid<352) + A2/embedding (bid>=352).
// ---------------------------------------------------------------------------
#define PREP_V4 (4096 + TT * DM / 4)
#define WT_BLOCKS 352
#define PW_BLOCKS (WT_BLOCKS + (PREP_V4 + 255) / 256)

__global__ __launch_bounds__(256) void prep_wtrans(
    const float* __restrict__ in_proj_w, __hip_bfloat16* __restrict__ inWt,
    const float* __restrict__ dt_w, __hip_bfloat16* __restrict__ dtWt,
    const float* __restrict__ out_w, __hip_bfloat16* __restrict__ oWt,
    const float* __restrict__ head_w, __hip_bfloat16* __restrict__ headWt,
    const float* __restrict__ x_proj_w, __hip_bfloat16* __restrict__ xpWt,
    const float* __restrict__ A_log, float* __restrict__ A2,
    const int* __restrict__ bytes, const float* __restrict__ embed_w,
    float* __restrict__ x, __hip_bfloat16* __restrict__ xb) {
  __shared__ float tile[64][65];
  int bid = blockIdx.x;
  int tid = threadIdx.x;
  if (bid >= WT_BLOCKS) {  // ---- prep path ----
    int i = (bid - WT_BLOCKS) * 256 + tid;
    if (i >= PREP_V4) return;
    if (i < 4096) {
      f32x4 a = *(const f32x4*)(A_log + i * 4);
      f32x4 o;
#pragma unroll
      for (int j = 0; j < 4; ++j) o[j] = -fexp(a[j]) * LOG2E;
      *(f32x4*)(A2 + i * 4) = o;
      return;
    }
    i -= 4096;
    int t = i >> 6;
    int c4 = (i & 63) * 4;
    f32x4 v = *(const f32x4*)(embed_w + (size_t)bytes[t] * DM + c4);
    *(f32x4*)(x + (size_t)t * DM + c4) = v;
    bf16x4 ob;
#pragma unroll
    for (int j = 0; j < 4; ++j) ob[j] = (__bf16)v[j];
    *(bf16x4*)((__bf16*)xb + (size_t)t * DM + c4) = ob;
    return;
  }
  // ---- wtrans path ----
  const float* src;
  __hip_bfloat16* dst;
  int K, N, kt, nt, nw = 64;
  if (bid < 128) {        // in_proj: [256][1024] -> [1024][256]
    int l = bid >> 6, r = bid & 63;
    src = in_proj_w + (size_t)l * 262144; dst = inWt + (size_t)l * 262144;
    K = 256; N = 1024; kt = r >> 4; nt = r & 15;
  } else if (bid < 256) { // dt: [512][512] -> [512][512]
    int i = bid - 128; int l = i >> 6, r = i & 63;
    src = dt_w + (size_t)l * 262144; dst = dtWt + (size_t)l * 262144;
    K = 512; N = 512; kt = r >> 3; nt = r & 7;
  } else if (bid < 320) { // out: [512][256] -> [256][512]
    int i = bid - 256; int l = i >> 5, r = i & 31;
    src = out_w + (size_t)l * 131072; dst = oWt + (size_t)l * 131072;
    K = 512; N = 256; kt = r >> 2; nt = r & 3;
  } else if (bid < 336) { // head: [256][256] -> [256][256]
    int r = bid - 320;
    src = head_w; dst = headWt;
    K = 256; N = 256; kt = r >> 2; nt = r & 3;
  } else {                // x_proj: [512][32] -> [32][512] (64x32 tiles)
    int i = bid - 336; int l = i >> 3, r = i & 7;
    src = x_proj_w + (size_t)l * 16384; dst = xpWt + (size_t)l * 16384;
    K = 512; N = 32; kt = r; nt = 0; nw = 32;
  }
  int k0 = kt * 64, n0 = nt * 64;
  if (nw == 64) {
    int r0 = tid >> 4, c4 = (tid & 15) * 4;
#pragma unroll
    for (int rr = 0; rr < 4; ++rr) {
      int r = rr * 16 + r0;
      f32x4 v = *(const f32x4*)(src + (size_t)(k0 + r) * N + n0 + c4);
      tile[r][c4] = v[0]; tile[r][c4 + 1] = v[1]; tile[r][c4 + 2] = v[2]; tile[r][c4 + 3] = v[3];
    }
    __syncthreads();
    int n = tid >> 2, kc = (tid & 3) * 16;
#pragma unroll
    for (int cc = 0; cc < 2; ++cc) {
      int k = kc + cc * 8;
      bf16x8 o;
#pragma unroll
      for (int j = 0; j < 8; ++j) o[j] = (__bf16)tile[k + j][n];
      *(bf16x8*)((__bf16*)dst + (size_t)(n0 + n) * K + k0 + k) = o;
    }
  } else {
    int r0 = tid >> 3, c4 = (tid & 7) * 4;
#pragma unroll
    for (int rr = 0; rr < 2; ++rr) {
      int r = rr * 32 + r0;
      f32x4 v = *(const f32x4*)(src + (size_t)(k0 + r) * N + c4);
      tile[r][c4] = v[0]; tile[r][c4 + 1] = v[1]; tile[r][c4 + 2] = v[2]; tile[r][c4 + 3] = v[3];
    }
    __syncthreads();
    int n = tid >> 3, kc = (tid & 7) * 8;
    bf16x8 o;
#pragma unroll
    for (int j = 0; j < 8; ++j) o[j] = (__bf16)tile[kc + j][n];
    *(bf16x8*)((__bf16*)dst + (size_t)n * K + k0 + kc) = o;
  }
}

// ---------------------------------------------------------------------------
// Fully-fused Mamba layer, TW=16 WITH xbs LDS staging (the untested quadrant:
// round 8's TW=16 failed via direct-global A-gather, rounds 3/7 via (512,8)
// VGPR-32 spills; this keeps the round-5 staged structure at half tile).
// LDS: xbs[32][264] + xcs[19][520] + Bms[16][20] = 37.9KB -> 4 blocks/CU,
// grid 1024, VGPR ~64 -> 8 waves/SIMD (2x round-11's wave pool; independent
// blocks fill each other's barrier drains).
// A-row-tiles overlap for the conv halo: x_in tiles at xbs rows {13,16} ->
// xcs rows {0..15, 3..18} (rows 3..15 dup-stored bit-identical); z = tile
// at xbs rows 16..31 (tokens t0..t0+15), kept in registers.
// DOHEAD (last layer): head-GEMM+entropy in-block, ent is the only output.
// ---------------------------------------------------------------------------
template <bool DOHEAD>
__global__ __launch_bounds__(512, 4) void mamba_fused(
    const __hip_bfloat16* __restrict__ xbin,  // [TT][256] layer input (bf16)
    __hip_bfloat16* __restrict__ xbout,       // [TT][256] layer output (bf16)
    const __bf16* __restrict__ inW,           // [1024][256] W^T
    const __bf16* __restrict__ dtW,           // [512][512]  W^T
    const __bf16* __restrict__ oW,            // [256][512]  W^T
    const __bf16* __restrict__ xpW,           // [32][512]   W^T (rows 0..15 = B)
    const float* __restrict__ cw, const float* __restrict__ cb,
    const float* __restrict__ A2, const float* __restrict__ dtb,
    const float* __restrict__ Dp, const float* __restrict__ nw,
    float* __restrict__ x,
    const __bf16* __restrict__ hW, float* __restrict__ ent) {
  extern __shared__ char smem[];
  __bf16* xbs = (__bf16*)smem;                             // [32][XBST]
  __bf16* xcs = (__bf16*)(smem + 32 * XBST * 2);           // [19][XST]: xin -> xc -> y'
  float* Bms = (float*)(smem + 32 * XBST * 2 + 19 * XST * 2);  // [16][BMST]
  float* vst = (float*)smem;                               // [16][VST] f32 overlay (epilogue)

  int tid = threadIdx.x;
  int lane = tid & 63;
  int w = tid >> 6;          // 8 waves
  int quad = lane >> 4;
  int l15 = lane & 15;
  int t0 = blockIdx.x * TW;
  int s0 = t0 & (SS - 1);

  // ---- S: stage A-tile xb[t0-16 .. t0+15] -> xbs (32x256, coalesced) ----
#pragma unroll
  for (int it = 0; it < 2; ++it) {
    int idx = it * 512 + tid;
    int r = idx >> 5, c8 = (idx & 31) * 8;
    int tok = t0 - 16 + r;
    if (tok < 0) tok = 0;  // only block 0; halo results unused there (s0==0)
    *(bf16x8*)(xbs + r * XBST + c8) =
        *(const bf16x8*)((const __bf16*)xbin + (size_t)tok * DM + c8);
  }
  __syncthreads();

  // ---- G1: x_in = xbtile @ inW^T cols [w*64,+64), A-tiles at xbs rows
  //      {13,16} -> xcs rows {0..15, 3..18} (3..15 dup, bit-identical). ----
  int wn64 = w * 64;
#pragma unroll 1
  for (int cth = 0; cth < 2; ++cth) {
    const __bf16* bp = inW + (size_t)(wn64 + cth * 32 + l15) * DM + quad * 8;
    f32x4 ga[2][2] = {};
    bf16x8 bnx[2];
#pragma unroll
    for (int ni = 0; ni < 2; ++ni)
      bnx[ni] = *(const bf16x8*)(bp + (size_t)ni * 16 * DM);
#pragma unroll
    for (int kk = 0; kk < 8; ++kk) {
      int k0 = kk * 32;
      bf16x8 bcur[2];
#pragma unroll
      for (int ni = 0; ni < 2; ++ni) bcur[ni] = bnx[ni];
      if (kk < 7) {
#pragma unroll
        for (int ni = 0; ni < 2; ++ni)
          bnx[ni] = *(const bf16x8*)(bp + (size_t)ni * 16 * DM + k0 + 32);
      }
      bf16x8 af0 = *(const bf16x8*)(xbs + (13 + l15) * XBST + k0 + quad * 8);
      bf16x8 af1 = *(const bf16x8*)(xbs + (16 + l15) * XBST + k0 + quad * 8);
#pragma unroll
      for (int ni = 0; ni < 2; ++ni) {
        ga[0][ni] = __builtin_amdgcn_mfma_f32_16x16x32_bf16(af0, bcur[ni], ga[0][ni], 0, 0, 0);
        ga[1][ni] = __builtin_amdgcn_mfma_f32_16x16x32_bf16(af1, bcur[ni], ga[1][ni], 0, 0, 0);
      }
    }
#pragma unroll
    for (int rt = 0; rt < 2; ++rt) {
      int roff = rt * 3;  // tiles land at xcs row-offsets {0,3}
#pragma unroll
      for (int ni = 0; ni < 2; ++ni)
#pragma unroll
        for (int rg = 0; rg < 4; ++rg) {
          int row = roff + quad * 4 + rg;
          xcs[row * XST + wn64 + cth * 32 + ni * 16 + l15] = (__bf16)ga[rt][ni][rg];
        }
    }
  }
  __syncthreads();  // xin (rows 0..18) complete in LDS

  // ---- P0: conv+silu IN-PLACE on xcs (halo rows 0..2, tokens rows 3..18) ----
  {
    int d = tid;
    float wv[4];
#pragma unroll
    for (int k = 0; k < 4; ++k) wv[k] = cw[d * 4 + k];
    float b = cb[d];
    float h0 = 0, h1 = 0, h2 = 0;
    if (s0 > 0) {
      h0 = (float)xcs[0 * XST + d];
      h1 = (float)xcs[1 * XST + d];
      h2 = (float)xcs[2 * XST + d];
    }
#pragma unroll 4
    for (int s = 0; s < TW; ++s) {
      float c = (float)xcs[(s + 3) * XST + d];
      float a = b + wv[0] * h0 + wv[1] * h1 + wv[2] * h2 + wv[3] * c;
      xcs[(s + 3) * XST + d] = (__bf16)(a * fsigmoid(a));
      h0 = h1; h1 = h2; h2 = c;
    }
  }
  __syncthreads();

  // ---- P1: Bmat = xc @ xpW^T (wave 0 only; overlapped with P2 of waves 1-7) ----
  if (w == 0) {
    f32x4 bacc = {};
#pragma unroll
    for (int k0 = 0; k0 < DI; k0 += 32) {
      bf16x8 a = *(const bf16x8*)(xcs + (l15 + 3) * XST + k0 + quad * 8);
      bf16x8 bb = *(const bf16x8*)(xpW + l15 * DI + k0 + quad * 8);
      bacc = __builtin_amdgcn_mfma_f32_16x16x32_bf16(a, bb, bacc, 0, 0, 0);
    }
#pragma unroll
    for (int rg = 0; rg < 4; ++rg)
      Bms[(quad * 4 + rg) * BMST + l15] = bacc[rg];
  }

  // ---- P2: dt-GEMM: dtlin = xc @ dtW^T, wave owns channels [w*64,+64). ----
  int dbase = w * 64;
  const __bf16* dtWp = dtW + (size_t)(dbase + l15) * DI + quad * 8;
  f32x4 acc[4] = {};
  {
    bf16x8 bnx[4];
#pragma unroll
    for (int ni = 0; ni < 4; ++ni)
      bnx[ni] = *(const bf16x8*)(dtWp + (size_t)ni * 16 * DI);
#pragma unroll
    for (int kk = 0; kk < 16; ++kk) {
      int k0 = kk * 32;
      bf16x8 bcur[4];
#pragma unroll
      for (int ni = 0; ni < 4; ++ni) bcur[ni] = bnx[ni];
      if (kk < 15) {
#pragma unroll
        for (int ni = 0; ni < 4; ++ni)
          bnx[ni] = *(const bf16x8*)(dtWp + (size_t)ni * 16 * DI + k0 + 32);
      }
      bf16x8 af = *(const bf16x8*)(xcs + (l15 + 3) * XST + k0 + quad * 8);
#pragma unroll
      for (int ni = 0; ni < 4; ++ni)
        acc[ni] = __builtin_amdgcn_mfma_f32_16x16x32_bf16(af, bcur[ni], acc[ni], 0, 0, 0);
    }
  }

  // ---- G2: z = xbtile @ inW^T cols [512+w*64,+64), A = xbs rows 16..31
  //      (tokens t0..t0+15) -> REGISTERS ONLY. ----
  bf16x4 zsave[2][2];
#pragma unroll
  for (int cth = 0; cth < 2; ++cth) {
    const __bf16* bp = inW + (size_t)(512 + wn64 + cth * 32 + l15) * DM + quad * 8;
    f32x4 gz[2] = {};
    bf16x8 bnx[2];
#pragma unroll
    for (int ni = 0; ni < 2; ++ni)
      bnx[ni] = *(const bf16x8*)(bp + (size_t)ni * 16 * DM);
#pragma unroll
    for (int kk = 0; kk < 8; ++kk) {
      int k0 = kk * 32;
      bf16x8 bcur[2];
#pragma unroll
      for (int ni = 0; ni < 2; ++ni) bcur[ni] = bnx[ni];
      if (kk < 7) {
#pragma unroll
        for (int ni = 0; ni < 2; ++ni)
          bnx[ni] = *(const bf16x8*)(bp + (size_t)ni * 16 * DM + k0 + 32);
      }
      bf16x8 af = *(const bf16x8*)(xbs + (16 + l15) * XBST + k0 + quad * 8);
#pragma unroll
      for (int ni = 0; ni < 2; ++ni)
        gz[ni] = __builtin_amdgcn_mfma_f32_16x16x32_bf16(af, bcur[ni], gz[ni], 0, 0, 0);
    }
#pragma unroll
    for (int ni = 0; ni < 2; ++ni)
#pragma unroll
      for (int rg = 0; rg < 4; ++rg)
        zsave[cth][ni][rg] = (__bf16)gz[ni][rg];
  }
  __syncthreads();  // Bms visible; all xcs/xbs reads (P1/P2/G2) done

  // ---- P2b: ssm in-register + fold silu(z) from zsave; write y' to own slab ----
#pragma unroll
  for (int ni = 0; ni < 4; ++ni) {
    int d = dbase + ni * 16 + l15;
    float dtbv = dtb[d];
    float dpv = Dp[d];
    const f32x4* ar = (const f32x4*)(A2 + d * DSTATE);
    f32x4 av[4];
#pragma unroll
    for (int q = 0; q < 4; ++q) av[q] = ar[q];
#pragma unroll
    for (int rg = 0; rg < 4; ++rg) {
      int tl = quad * 4 + rg;
      const f32x4* br = (const f32x4*)(Bms + tl * BMST);
      float dt = fsoftplus(acc[ni][rg] + dtbv);
      float s = 0.f;
#pragma unroll
      for (int q = 0; q < 4; ++q) {
        f32x4 bq = br[q];
#pragma unroll
        for (int j = 0; j < 4; ++j) s += fexp2(av[q][j] * dt) * bq[j];
      }
      float xcv = (float)xcs[(tl + 3) * XST + d];
      float y = dt * xcv * s + dpv * xcv;
      float zf = (float)zsave[ni >> 1][ni & 1][rg];
      xcs[(tl + 3) * XST + d] = (__bf16)(y * zf * fsigmoid(zf));
    }
  }
  __syncthreads();  // y' complete block-wide

  // ---- P5: out-GEMM: yout = y' @ oW^T, wave owns cols [w*32,+32). ----
  int wn = w * 32;
  const __bf16* oWp = oW + (size_t)(wn + l15) * DI + quad * 8;
  f32x4 oacc[2] = {};
  {
    bf16x8 onx[2];
#pragma unroll
    for (int ni = 0; ni < 2; ++ni)
      onx[ni] = *(const bf16x8*)(oWp + (size_t)ni * 16 * DI);
#pragma unroll
    for (int kk = 0; kk < 16; ++kk) {
      int k0 = kk * 32;
      bf16x8 ocur[2];
#pragma unroll
      for (int ni = 0; ni < 2; ++ni) ocur[ni] = onx[ni];
      if (kk < 15) {
#pragma unroll
        for (int ni = 0; ni < 2; ++ni)
          onx[ni] = *(const bf16x8*)(oWp + (size_t)ni * 16 * DI + k0 + 32);
      }
      bf16x8 af = *(const bf16x8*)(xcs + (l15 + 3) * XST + k0 + quad * 8);
#pragma unroll
      for (int ni = 0; ni < 2; ++ni)
        oacc[ni] = __builtin_amdgcn_mfma_f32_16x16x32_bf16(af, ocur[ni], oacc[ni], 0, 0, 0);
    }
  }
  __syncthreads();  // all xcs reads done; safe to overlay vst

  // ---- P6a: scatter yout into vst (f32 overlay) ----
#pragma unroll
  for (int ni = 0; ni < 2; ++ni)
#pragma unroll
    for (int rg = 0; rg < 4; ++rg) {
      int tl = quad * 4 + rg;
      vst[tl * VST + wn + ni * 16 + l15] = oacc[ni][rg];
    }
  __syncthreads();

  // ---- P6b: row-major epilogue: residual + rmsnorm, full-line writes. ----
  {
    int row = tid >> 5;       // 0..15
    int seg = tid & 31;
    int c0 = seg * 8;
    const float* xr = x + (size_t)(t0 + row) * DM + c0;
    f32x4 xv0 = *(const f32x4*)(xr);
    f32x4 xv1 = *(const f32x4*)(xr + 4);
    float vv[8];
    float sq = 0.f;
#pragma unroll
    for (int j = 0; j < 4; ++j) {
      float v = vst[row * VST + c0 + j] + xv0[j];
      vv[j] = v; sq += v * v;
    }
#pragma unroll
    for (int j = 0; j < 4; ++j) {
      float v = vst[row * VST + c0 + 4 + j] + xv1[j];
      vv[4 + j] = v; sq += v * v;
    }
    sq += __shfl_xor(sq, 1);
    sq += __shfl_xor(sq, 2);
    sq += __shfl_xor(sq, 4);
    sq += __shfl_xor(sq, 8);
    sq += __shfl_xor(sq, 16);
    float r = rsqrtf(sq * (1.f / DM) + RMS_EPS);
    f32x4 nv0 = *(const f32x4*)(nw + c0);
    f32x4 nv1 = *(const f32x4*)(nw + c0 + 4);
    bf16x8 ob;
    f32x4 o0, o1;
#pragma unroll
    for (int j = 0; j < 4; ++j) {
      float v = vv[j] * r * nv0[j];
      o0[j] = v; ob[j] = (__bf16)v;
    }
#pragma unroll
    for (int j = 0; j < 4; ++j) {
      float v = vv[4 + j] * r * nv1[j];
      o1[j] = v; ob[4 + j] = (__bf16)v;
    }
    if constexpr (!DOHEAD) {
      float* xw = x + (size_t)(t0 + row) * DM + c0;
      __hip_bfloat16* xbw = xbout + (size_t)(t0 + row) * DM + c0;
      *(f32x4*)(xw) = o0;
      *(f32x4*)(xw + 4) = o1;
      *(bf16x8*)(xbw) = ob;
    } else {
      __bf16* hts = (__bf16*)(smem + HTS_OFF);
      *(bf16x8*)(hts + row * HST3 + c0) = ob;
    }
  }

  // ---- H: fused head-GEMM + entropy (last layer only). Wave w owns vocab
  //      cols [w*32,+32); logits bit-identical to the old head_entropy. ----
  if constexpr (DOHEAD) {
    __bf16* hts = (__bf16*)(smem + HTS_OFF);
    float* red = (float*)(smem + RED_OFF);  // [16][8][2], reuses dead Bms
    __syncthreads();
    int wv = w * 32;
    const __bf16* hp = hW + (size_t)(wv + l15) * DM + quad * 8;
    f32x4 hacc[2] = {};
#pragma unroll
    for (int kk = 0; kk < 8; ++kk) {
      int k0 = kk * 32;
      bf16x8 b0 = *(const bf16x8*)(hp + k0);
      bf16x8 b1 = *(const bf16x8*)(hp + (size_t)16 * DM + k0);
      bf16x8 a = *(const bf16x8*)(hts + l15 * HST3 + k0 + quad * 8);
      hacc[0] = __builtin_amdgcn_mfma_f32_16x16x32_bf16(a, b0, hacc[0], 0, 0, 0);
      hacc[1] = __builtin_amdgcn_mfma_f32_16x16x32_bf16(a, b1, hacc[1], 0, 0, 0);
    }
#pragma unroll
    for (int rg = 0; rg < 4; ++rg) {
      float l0 = hacc[0][rg], l1 = hacc[1][rg];
      float e0 = fexp(l0), e1 = fexp(l1);
      float s = e0 + e1;
      float u = e0 * l0 + e1 * l1;
      s += __shfl_xor(s, 1); u += __shfl_xor(u, 1);
      s += __shfl_xor(s, 2); u += __shfl_xor(u, 2);
      s += __shfl_xor(s, 4); u += __shfl_xor(u, 4);
      s += __shfl_xor(s, 8); u += __shfl_xor(u, 8);
      if (l15 == 0) {
        int tl = quad * 4 + rg;
        red[(tl * 8 + w) * 2] = s;
        red[(tl * 8 + w) * 2 + 1] = u;
      }
    }
    __syncthreads();
    if (tid < 16) {
      float s = 0.f, u = 0.f;
#pragma unroll
      for (int ww = 0; ww < 8; ++ww) {
        s += red[(tid * 8 + ww) * 2];
        u += red[(tid * 8 + ww) * 2 + 1];
      }
      ent[t0 + tid] = (flog(s) - u * frcp(s)) * (1.f / LOG_VOCAB);
    }
  }
}

// ---------------------------------------------------------------------------
// Parallel boundary scan (anchors via block max-scan). BB blocks x 256 thr.
// ---------------------------------------------------------------------------
__global__ __launch_bounds__(256) void scan_kernel(
    const float* __restrict__ ent, float* __restrict__ btp_out,
    int* __restrict__ pstart, int* __restrict__ npatch) {
  __shared__ int sh[256];
  int b = blockIdx.x, t = threadIdx.x;
  int sbase = t * 8;
  f32x4 e0 = *(const f32x4*)(ent + (size_t)b * SS + sbase);
  f32x4 e1 = *(const f32x4*)(ent + (size_t)b * SS + sbase + 4);
  float e[8] = {e0[0], e0[1], e0[2], e0[3], e1[0], e1[1], e1[2], e1[3]};
  int la = -1;
  unsigned cbits = 0;
#pragma unroll
  for (int j = 0; j < 8; ++j) {
    int s = sbase + j;
    bool cb = (s == 0) || (e[j] > THR_);
    if (cb) { la = s; cbits |= 1u << j; }
  }
  sh[t] = la;
  __syncthreads();
  int run = la;
  for (int off = 1; off < 256; off <<= 1) {
    int other = (t >= off) ? sh[t - off] : -1;
    __syncthreads();
    run = max(run, other);
    sh[t] = run;
    __syncthreads();
  }
  int anchor = (t > 0) ? sh[t - 1] : -1;
  unsigned bits = 0;
#pragma unroll
  for (int j = 0; j < 8; ++j) {
    int s = sbase + j;
    bool cb = (cbits >> j) & 1u;
    bool bnd;
    if (cb) { bnd = true; anchor = s; }
    else bnd = ((s - anchor) & 7) == 0;
    bits |= (unsigned)bnd << j;
  }
  int cnt = __popc(bits);
  __syncthreads();
  sh[t] = cnt;
  __syncthreads();
  int runc = cnt;
  for (int off = 1; off < 256; off <<= 1) {
    int other = (t >= off) ? sh[t - off] : 0;
    __syncthreads();
    runc += other;
    sh[t] = runc;
    __syncthreads();
  }
  if (t == 255) npatch[b] = runc;
  int btp = (runc - cnt) - 1;
#pragma unroll
  for (int j = 0; j < 8; ++j) {
    int s = sbase + j;
    if ((bits >> j) & 1u) { ++btp; pstart[b * SS + btp] = s; }
    btp_out[b * SS + s] = (float)btp;
  }
}

// ---------------------------------------------------------------------------
// patch mean pooling: 2048 blocks, 8 patches/block, 32 threads/patch.
// ---------------------------------------------------------------------------
__global__ __launch_bounds__(256) void patch_kernel(
    const float* __restrict__ bemb, const int* __restrict__ pstart,
    const int* __restrict__ npatch, float* __restrict__ pe_out,
    float* __restrict__ plen_out) {
  int bp8 = blockIdx.x;            // 0..2047
  int b = bp8 >> 8;                // 256 blocks per batch
  int p0 = (bp8 & 255) * 8;
  int t = threadIdx.x;
  int g = t >> 5;                  // patch group 0..7
  int t32 = t & 31;
  int p = p0 + g;
  int np = npatch[b];
  size_t outbase = ((size_t)b * SS + p) * DM + t32 * 8;
  if (p >= np) {
    f32x4 z = {0.f, 0.f, 0.f, 0.f};
    *(f32x4*)(pe_out + outbase) = z;
    *(f32x4*)(pe_out + outbase + 4) = z;
    if (t32 == 0) plen_out[b * SS + p] = 0.f;
    return;
  }
  int start = pstart[b * SS + p];
  int end = (p + 1 < np) ? pstart[b * SS + p + 1] : SS;
  f32x4 a0 = {0.f, 0.f, 0.f, 0.f}, a1 = {0.f, 0.f, 0.f, 0.f};
  for (int r = start; r < end; ++r) {
    const float* row = bemb + ((size_t)b * SS + r) * DM + t32 * 8;
    f32x4 v0 = *(const f32x4*)row;
    f32x4 v1 = *(const f32x4*)(row + 4);
#pragma unroll
    for (int j = 0; j < 4; ++j) { a0[j] += v0[j]; a1[j] += v1[j]; }
  }
  float inv = frcp((float)(end - start));
#pragma unroll
  for (int j = 0; j < 4; ++j) { a0[j] *= inv; a1[j] *= inv; }
  *(f32x4*)(pe_out + outbase) = a0;
  *(f32x4*)(pe_out + outbase + 4) = a1;
  if (t32 == 0) plen_out[b * SS + p] = (float)(end - start);
}

// ---------------------------------------------------------------------------
// Launcher — 5 dispatches total
// ---------------------------------------------------------------------------
extern "C" void kernel_launch(void* const* d_in, const int* in_sizes, int n_in,
                              void* d_out, int out_size, void* d_ws, size_t ws_size,
                              hipStream_t stream) {
  const int* bytes = (const int*)d_in[0];
  const float* bemb = (const float*)d_in[1];
  const float* embed_w = (const float*)d_in[2];
  const float* in_proj_w = (const float*)d_in[3];
  const float* conv_w = (const float*)d_in[4];
  const float* conv_b = (const float*)d_in[5];
  const float* x_proj_w = (const float*)d_in[6];
  const float* dt_w = (const float*)d_in[7];
  const float* dt_b = (const float*)d_in[8];
  const float* A_log = (const float*)d_in[9];
  const float* D_param = (const float*)d_in[10];
  const float* out_w = (const float*)d_in[11];
  const float* norm_w = (const float*)d_in[12];
  const float* head_w = (const float*)d_in[13];

  float* out = (float*)d_out;
  float* pe_out = out;                      // (B,S,DM)
  float* plen_out = out + (size_t)TT * DM;  // (B,S)
  float* btp_out = plen_out + TT;           // (B,S)

  char* wsb = (char*)d_ws;
  size_t off = 0;
  auto alloc = [&](size_t bytes_) -> void* {
    void* p = wsb + off;
    off += (bytes_ + 255) & ~(size_t)255;
    return p;
  };
  float* A2 = (float*)alloc((size_t)NLAYERS * DI * DSTATE * 4);
  float* x = (float*)alloc((size_t)TT * DM * 4);
  __hip_bfloat16* xb0 = (__hip_bfloat16*)alloc((size_t)TT * DM * 2);
  __hip_bfloat16* xb1 = (__hip_bfloat16*)alloc((size_t)TT * DM * 2);
  float* ent = (float*)alloc((size_t)TT * 4);
  int* pstart = (int*)alloc((size_t)TT * 4);
  int* npatch = (int*)alloc(256);
  __hip_bfloat16* inWt = (__hip_bfloat16*)alloc((size_t)NLAYERS * 2 * DI * DM * 2);
  __hip_bfloat16* dtWt = (__hip_bfloat16*)alloc((size_t)NLAYERS * DI * DI * 2);
  __hip_bfloat16* oWt = (__hip_bfloat16*)alloc((size_t)NLAYERS * DM * DI * 2);
  __hip_bfloat16* xpWt = (__hip_bfloat16*)alloc((size_t)NLAYERS * 32 * DI * 2);
  __hip_bfloat16* headWt = (__hip_bfloat16*)alloc((size_t)VOCAB * DM * 2);

  // 1: weight transposes + A2 + embedding (merged)
  prep_wtrans<<<PW_BLOCKS, 256, 0, stream>>>(
      in_proj_w, inWt, dt_w, dtWt, out_w, oWt, head_w, headWt,
      x_proj_w, xpWt, A_log, A2, bytes, embed_w, x, xb0);

  // 2: Mamba layer 0 (writes x, xb1)
  size_t fused_lds = (size_t)32 * XBST * 2 + (size_t)19 * XST * 2 + (size_t)TW * BMST * 4;
  mamba_fused<false><<<TT / TW, 512, fused_lds, stream>>>(
      xb0, xb1,
      (const __bf16*)inWt, (const __bf16*)dtWt, (const __bf16*)oWt,
      (const __bf16*)xpWt,
      conv_w, conv_b, A2, dt_b, D_param, norm_w, x, nullptr, nullptr);

  // 3: Mamba layer 1 + fused head-GEMM + entropy (writes ent only)
  mamba_fused<true><<<TT / TW, 512, fused_lds, stream>>>(
      xb1, xb0,
      (const __bf16*)(inWt + (size_t)1 * 2 * DI * DM),
      (const __bf16*)(dtWt + (size_t)1 * DI * DI),
      (const __bf16*)(oWt + (size_t)1 * DM * DI),
      (const __bf16*)(xpWt + (size_t)1 * 32 * DI),
      conv_w + (size_t)1 * DI * DCONV, conv_b + (size_t)1 * DI,
      A2 + (size_t)1 * DI * DSTATE, dt_b + (size_t)1 * DI,
      D_param + (size_t)1 * DI, norm_w + (size_t)1 * DM, x,
      (const __bf16*)headWt, ent);

  // 4: boundary scan (parallel)
  scan_kernel<<<BB, 256, 0, stream>>>(ent, btp_out, pstart, npatch);

  // 5: patch mean pooling (8 patches/block)
  patch_kernel<<<TT / 8, 256, 0, stream>>>(bemb, pstart, npatch, pe_out, plen_out);
}

// Round 13
// 301.778 us; speedup vs baseline: 1.5157x; 1.5157x over previous
//
#include <hip/hip_runtime.h>
#include <hip/hip_bf16.h>
#include <math.h>

// Problem constants
#define BB 8
#define SS 2048
#define TT (BB * SS)      // 16384 tokens
#define DM 256
#define DI 512
#define DSTATE 16
#define DCONV 4
#define NLAYERS 2
#define VOCAB 256
#define LOG_VOCAB 5.545177444479562f
#define RMS_EPS 1.1920929e-07f
#define LOG2E 1.4426950408889634f
#define LN2 0.6931471805599453f
#define THR_ 0.5f

#define TW 32            // tokens per fused block: grid 512 -> 2 blocks/CU
#define XBST 264         // xbs (A-tile) LDS row stride (bf16): 528B -> 2-way aliasing only
#define XST 520          // xcs LDS row stride (bf16 elems): 1040B -> 2-way bank aliasing only
#define BMST 20          // Bms LDS row stride (f32)
#define VST 260          // vst (f32 epilogue overlay) row stride
#define HST3 264         // hts (head A-tile) row stride (bf16)
// LDS layout: xbs [0,25344) | xcs [25344,61744) | Bms [61744,64304)
// overlays (xcs dead after P5): vst 33280B @25344 (!DOHEAD);
//   hts 16896B @25344 + rmsp 1024B @42240 (DOHEAD); red 2048B @61744 (Bms dead)
#define XBS_BYTES 25344
#define VST_OFF 25344
#define HTS_OFF 25344
#define RMSP_OFF 42240
#define RED_OFF 61744

typedef __attribute__((ext_vector_type(8))) __bf16 bf16x8;
typedef __attribute__((ext_vector_type(4))) __bf16 bf16x4;
typedef __attribute__((ext_vector_type(2))) __bf16 bf16x2;
typedef __attribute__((ext_vector_type(4))) float f32x4;

// ---- fast transcendentals (1-ulp class; entropy margin vs THR=0.5 is ~0.4) ----
__device__ __forceinline__ float fexp(float x) { return __builtin_amdgcn_exp2f(x * LOG2E); }
__device__ __forceinline__ float fexp2(float x) { return __builtin_amdgcn_exp2f(x); }
__device__ __forceinline__ float flog(float x) { return __builtin_amdgcn_logf(x) * LN2; }
__device__ __forceinline__ float frcp(float x) { return __builtin_amdgcn_rcpf(x); }
__device__ __forceinline__ float fsigmoid(float x) { return frcp(1.f + fexp(-x)); }
__device__ __forceinline__ float fsoftplus(float x) {
  return fmaxf(x, 0.f) + flog(1.f + fexp(-fabsf(x)));
}

// ---------------------------------------------------------------------------
// prep_wtrans: merged weight transposes (bid<352) + A2/embedding (bid>=352).
// Embedding now writes ONLY xb (bf16): the f32 x residual stream is deleted
// (residual == previous layer's normalized output == xb, bf16-rounded; final
// outputs depend on the mamba stream only through discrete boundaries,
// margin ~0.4 vs THR).
// ---------------------------------------------------------------------------
#define PREP_V4 (4096 + TT * DM / 4)
#define WT_BLOCKS 352
#define PW_BLOCKS (WT_BLOCKS + (PREP_V4 + 255) / 256)

__global__ __launch_bounds__(256) void prep_wtrans(
    const float* __restrict__ in_proj_w, __hip_bfloat16* __restrict__ inWt,
    const float* __restrict__ dt_w, __hip_bfloat16* __restrict__ dtWt,
    const float* __restrict__ out_w, __hip_bfloat16* __restrict__ oWt,
    const float* __restrict__ head_w, __hip_bfloat16* __restrict__ headWt,
    const float* __restrict__ x_proj_w, __hip_bfloat16* __restrict__ xpWt,
    const float* __restrict__ A_log, float* __restrict__ A2,
    const int* __restrict__ bytes, const float* __restrict__ embed_w,
    __hip_bfloat16* __restrict__ xb) {
  __shared__ float tile[64][65];
  int bid = blockIdx.x;
  int tid = threadIdx.x;
  if (bid >= WT_BLOCKS) {  // ---- prep path ----
    int i = (bid - WT_BLOCKS) * 256 + tid;
    if (i >= PREP_V4) return;
    if (i < 4096) {
      f32x4 a = *(const f32x4*)(A_log + i * 4);
      f32x4 o;
#pragma unroll
      for (int j = 0; j < 4; ++j) o[j] = -fexp(a[j]) * LOG2E;
      *(f32x4*)(A2 + i * 4) = o;
      return;
    }
    i -= 4096;
    int t = i >> 6;
    int c4 = (i & 63) * 4;
    f32x4 v = *(const f32x4*)(embed_w + (size_t)bytes[t] * DM + c4);
    bf16x4 ob;
#pragma unroll
    for (int j = 0; j < 4; ++j) ob[j] = (__bf16)v[j];
    *(bf16x4*)((__bf16*)xb + (size_t)t * DM + c4) = ob;
    return;
  }
  // ---- wtrans path ----
  const float* src;
  __hip_bfloat16* dst;
  int K, N, kt, nt, nw = 64;
  if (bid < 128) {        // in_proj: [256][1024] -> [1024][256]
    int l = bid >> 6, r = bid & 63;
    src = in_proj_w + (size_t)l * 262144; dst = inWt + (size_t)l * 262144;
    K = 256; N = 1024; kt = r >> 4; nt = r & 15;
  } else if (bid < 256) { // dt: [512][512] -> [512][512]
    int i = bid - 128; int l = i >> 6, r = i & 63;
    src = dt_w + (size_t)l * 262144; dst = dtWt + (size_t)l * 262144;
    K = 512; N = 512; kt = r >> 3; nt = r & 7;
  } else if (bid < 320) { // out: [512][256] -> [256][512]
    int i = bid - 256; int l = i >> 5, r = i & 31;
    src = out_w + (size_t)l * 131072; dst = oWt + (size_t)l * 131072;
    K = 512; N = 256; kt = r >> 2; nt = r & 3;
  } else if (bid < 336) { // head: [256][256] -> [256][256]
    int r = bid - 320;
    src = head_w; dst = headWt;
    K = 256; N = 256; kt = r >> 2; nt = r & 3;
  } else {                // x_proj: [512][32] -> [32][512] (64x32 tiles)
    int i = bid - 336; int l = i >> 3, r = i & 7;
    src = x_proj_w + (size_t)l * 16384; dst = xpWt + (size_t)l * 16384;
    K = 512; N = 32; kt = r; nt = 0; nw = 32;
  }
  int k0 = kt * 64, n0 = nt * 64;
  if (nw == 64) {
    int r0 = tid >> 4, c4 = (tid & 15) * 4;
#pragma unroll
    for (int rr = 0; rr < 4; ++rr) {
      int r = rr * 16 + r0;
      f32x4 v = *(const f32x4*)(src + (size_t)(k0 + r) * N + n0 + c4);
      tile[r][c4] = v[0]; tile[r][c4 + 1] = v[1]; tile[r][c4 + 2] = v[2]; tile[r][c4 + 3] = v[3];
    }
    __syncthreads();
    int n = tid >> 2, kc = (tid & 3) * 16;
#pragma unroll
    for (int cc = 0; cc < 2; ++cc) {
      int k = kc + cc * 8;
      bf16x8 o;
#pragma unroll
      for (int j = 0; j < 8; ++j) o[j] = (__bf16)tile[k + j][n];
      *(bf16x8*)((__bf16*)dst + (size_t)(n0 + n) * K + k0 + k) = o;
    }
  } else {
    int r0 = tid >> 3, c4 = (tid & 7) * 4;
#pragma unroll
    for (int rr = 0; rr < 2; ++rr) {
      int r = rr * 32 + r0;
      f32x4 v = *(const f32x4*)(src + (size_t)(k0 + r) * N + c4);
      tile[r][c4] = v[0]; tile[r][c4 + 1] = v[1]; tile[r][c4 + 2] = v[2]; tile[r][c4 + 3] = v[3];
    }
    __syncthreads();
    int n = tid >> 3, kc = (tid & 7) * 8;
    bf16x8 o;
#pragma unroll
    for (int j = 0; j < 8; ++j) o[j] = (__bf16)tile[kc + j][n];
    *(bf16x8*)((__bf16*)dst + (size_t)n * K + k0 + kc) = o;
  }
}

// ---------------------------------------------------------------------------
// Fully-fused Mamba layer (round-11 body: TW=32 staged, 2-deep prefetch,
// (512,4), 102-110us — the established structural optimum).
// Round-13 change: the f32 x stream is GONE. Residual is read from the
// already-staged xbs LDS tile (rows 16..47 = this tile's input tokens):
// zero global residual traffic. vst overlays dead xcs (xbs must stay live).
// DOHEAD: epilogue runs column-partitioned (no vst needed — output goes to
// LDS hts, no global-coalescing concern); cross-wave rmsnorm via rmsp.
// ---------------------------------------------------------------------------
template <bool DOHEAD>
__global__ __launch_bounds__(512, 4) void mamba_fused(
    const __hip_bfloat16* __restrict__ xbin,  // [TT][256] layer input (bf16)
    __hip_bfloat16* __restrict__ xbout,       // [TT][256] layer output (bf16)
    const __bf16* __restrict__ inW,           // [1024][256] W^T
    const __bf16* __restrict__ dtW,           // [512][512]  W^T
    const __bf16* __restrict__ oW,            // [256][512]  W^T
    const __bf16* __restrict__ xpW,           // [32][512]   W^T (rows 0..15 = B)
    const float* __restrict__ cw, const float* __restrict__ cb,
    const float* __restrict__ A2, const float* __restrict__ dtb,
    const float* __restrict__ Dp, const float* __restrict__ nw,
    const __bf16* __restrict__ hW, float* __restrict__ ent) {
  extern __shared__ char smem[];
  __bf16* xbs = (__bf16*)smem;                       // [48][XBST], live to end
  __bf16* xcs = (__bf16*)(smem + XBS_BYTES);         // [35][XST]: xin -> xc -> y'
  float* Bms = (float*)(smem + XBS_BYTES + 35 * XST * 2);  // [32][BMST]

  int tid = threadIdx.x;
  int lane = tid & 63;
  int w = tid >> 6;          // 8 waves
  int quad = lane >> 4;
  int l15 = lane & 15;
  int t0 = blockIdx.x * TW;
  int s0 = t0 & (SS - 1);

  // ---- S: stage A-tile xb[t0-16 .. t0+31] -> xbs (48x256, coalesced) ----
#pragma unroll
  for (int it = 0; it < 3; ++it) {
    int idx = it * 512 + tid;
    int r = idx >> 5, c8 = (idx & 31) * 8;
    int tok = t0 - 16 + r;
    if (tok < 0) tok = 0;  // only block 0; halo unused there (s0==0)
    *(bf16x8*)(xbs + r * XBST + c8) =
        *(const bf16x8*)((const __bf16*)xbin + (size_t)tok * DM + c8);
  }
  __syncthreads();

  // ---- G1: x_in = xbtile @ inW^T cols [w*64,+64), 2-deep B prefetch. ----
  int wn64 = w * 64;
#pragma unroll 1
  for (int cth = 0; cth < 2; ++cth) {
    const __bf16* bp = inW + (size_t)(wn64 + cth * 32 + l15) * DM + quad * 8;
    f32x4 ga[3][2] = {};
    bf16x8 bnx0[2], bnx1[2];
#pragma unroll
    for (int ni = 0; ni < 2; ++ni) {
      bnx0[ni] = *(const bf16x8*)(bp + (size_t)ni * 16 * DM);
      bnx1[ni] = *(const bf16x8*)(bp + (size_t)ni * 16 * DM + 32);
    }
#pragma unroll
    for (int kk = 0; kk < 8; ++kk) {
      int k0 = kk * 32;
      bf16x8 bcur[2];
#pragma unroll
      for (int ni = 0; ni < 2; ++ni) { bcur[ni] = bnx0[ni]; bnx0[ni] = bnx1[ni]; }
      if (kk < 6) {
#pragma unroll
        for (int ni = 0; ni < 2; ++ni)
          bnx1[ni] = *(const bf16x8*)(bp + (size_t)ni * 16 * DM + k0 + 64);
      }
      bf16x8 af[3];
#pragma unroll
      for (int rt = 0; rt < 3; ++rt)
        af[rt] = *(const bf16x8*)(xbs + (rt * 16 + l15) * XBST + k0 + quad * 8);
#pragma unroll
      for (int rt = 0; rt < 3; ++rt)
#pragma unroll
        for (int ni = 0; ni < 2; ++ni)
          ga[rt][ni] = __builtin_amdgcn_mfma_f32_16x16x32_bf16(af[rt], bcur[ni], ga[rt][ni], 0, 0, 0);
    }
#pragma unroll
    for (int rt = 0; rt < 3; ++rt)
#pragma unroll
      for (int ni = 0; ni < 2; ++ni)
#pragma unroll
        for (int rg = 0; rg < 4; ++rg) {
          int grow = rt * 16 + quad * 4 + rg;
          if (grow >= 13)
            xcs[(grow - 13) * XST + wn64 + cth * 32 + ni * 16 + l15] = (__bf16)ga[rt][ni][rg];
        }
  }
  __syncthreads();  // xin complete in LDS (conv reads all cols)

  // ---- P0: conv+silu IN-PLACE on xcs (halo rows 0..2, tokens rows 3..34) ----
  {
    int d = tid;
    float wv[4];
#pragma unroll
    for (int k = 0; k < 4; ++k) wv[k] = cw[d * 4 + k];
    float b = cb[d];
    float h0 = 0, h1 = 0, h2 = 0;
    if (s0 > 0) {
      h0 = (float)xcs[0 * XST + d];
      h1 = (float)xcs[1 * XST + d];
      h2 = (float)xcs[2 * XST + d];
    }
#pragma unroll 4
    for (int s = 0; s < TW; ++s) {
      float c = (float)xcs[(s + 3) * XST + d];
      float a = b + wv[0] * h0 + wv[1] * h1 + wv[2] * h2 + wv[3] * c;
      xcs[(s + 3) * XST + d] = (__bf16)(a * fsigmoid(a));
      h0 = h1; h1 = h2; h2 = c;
    }
  }
  __syncthreads();

  // ---- P1: Bmat = xc @ xpW^T (waves 0-1; overlapped with P2 of waves 2-7) ----
  if (w < 2) {
    f32x4 bacc = {};
#pragma unroll
    for (int k0 = 0; k0 < DI; k0 += 32) {
      bf16x8 a = *(const bf16x8*)(xcs + (w * 16 + l15 + 3) * XST + k0 + quad * 8);
      bf16x8 bb = *(const bf16x8*)(xpW + l15 * DI + k0 + quad * 8);
      bacc = __builtin_amdgcn_mfma_f32_16x16x32_bf16(a, bb, bacc, 0, 0, 0);
    }
#pragma unroll
    for (int rg = 0; rg < 4; ++rg)
      Bms[(w * 16 + quad * 4 + rg) * BMST + l15] = bacc[rg];
  }

  // ---- P2: dt-GEMM, wave owns channels [w*64,+64). 2-deep B prefetch. ----
  int dbase = w * 64;
  const __bf16* dtWp = dtW + (size_t)(dbase + l15) * DI + quad * 8;
  f32x4 acc[2][4] = {};
  {
    bf16x8 bnx0[4], bnx1[4];
#pragma unroll
    for (int ni = 0; ni < 4; ++ni) {
      bnx0[ni] = *(const bf16x8*)(dtWp + (size_t)ni * 16 * DI);
      bnx1[ni] = *(const bf16x8*)(dtWp + (size_t)ni * 16 * DI + 32);
    }
#pragma unroll
    for (int kk = 0; kk < 16; ++kk) {
      int k0 = kk * 32;
      bf16x8 bcur[4];
#pragma unroll
      for (int ni = 0; ni < 4; ++ni) { bcur[ni] = bnx0[ni]; bnx0[ni] = bnx1[ni]; }
      if (kk < 14) {
#pragma unroll
        for (int ni = 0; ni < 4; ++ni)
          bnx1[ni] = *(const bf16x8*)(dtWp + (size_t)ni * 16 * DI + k0 + 64);
      }
      bf16x8 af[2];
#pragma unroll
      for (int mi = 0; mi < 2; ++mi)
        af[mi] = *(const bf16x8*)(xcs + (mi * 16 + l15 + 3) * XST + k0 + quad * 8);
#pragma unroll
      for (int mi = 0; mi < 2; ++mi)
#pragma unroll
        for (int ni = 0; ni < 4; ++ni)
          acc[mi][ni] = __builtin_amdgcn_mfma_f32_16x16x32_bf16(af[mi], bcur[ni], acc[mi][ni], 0, 0, 0);
    }
  }

  // ---- G2: z = xbtile @ inW^T cols [512+w*64,+64) -> REGISTERS. 2-deep. ----
  bf16x4 zsave[2][2][2];
#pragma unroll
  for (int cth = 0; cth < 2; ++cth) {
    const __bf16* bp = inW + (size_t)(512 + wn64 + cth * 32 + l15) * DM + quad * 8;
    f32x4 gz[2][2] = {};
    bf16x8 bnx0[2], bnx1[2];
#pragma unroll
    for (int ni = 0; ni < 2; ++ni) {
      bnx0[ni] = *(const bf16x8*)(bp + (size_t)ni * 16 * DM);
      bnx1[ni] = *(const bf16x8*)(bp + (size_t)ni * 16 * DM + 32);
    }
#pragma unroll
    for (int kk = 0; kk < 8; ++kk) {
      int k0 = kk * 32;
      bf16x8 bcur[2];
#pragma unroll
      for (int ni = 0; ni < 2; ++ni) { bcur[ni] = bnx0[ni]; bnx0[ni] = bnx1[ni]; }
      if (kk < 6) {
#pragma unroll
        for (int ni = 0; ni < 2; ++ni)
          bnx1[ni] = *(const bf16x8*)(bp + (size_t)ni * 16 * DM + k0 + 64);
      }
      bf16x8 af[2];
#pragma unroll
      for (int rt = 0; rt < 2; ++rt)
        af[rt] = *(const bf16x8*)(xbs + ((16 + rt * 16) + l15) * XBST + k0 + quad * 8);
#pragma unroll
      for (int rt = 0; rt < 2; ++rt)
#pragma unroll
        for (int ni = 0; ni < 2; ++ni)
          gz[rt][ni] = __builtin_amdgcn_mfma_f32_16x16x32_bf16(af[rt], bcur[ni], gz[rt][ni], 0, 0, 0);
    }
#pragma unroll
    for (int rt = 0; rt < 2; ++rt)
#pragma unroll
      for (int ni = 0; ni < 2; ++ni)
#pragma unroll
        for (int rg = 0; rg < 4; ++rg)
          zsave[cth][rt][ni][rg] = (__bf16)gz[rt][ni][rg];
  }
  __syncthreads();  // Bms visible; all full-width xcs reads (P1/P2) done

  // ---- P2b: ssm in-register + fold silu(z) from zsave; write y' to own slab ----
#pragma unroll
  for (int ni = 0; ni < 4; ++ni) {
    int d = dbase + ni * 16 + l15;
    float dtbv = dtb[d];
    float dpv = Dp[d];
    const f32x4* ar = (const f32x4*)(A2 + d * DSTATE);
    f32x4 av[4];
#pragma unroll
    for (int q = 0; q < 4; ++q) av[q] = ar[q];
#pragma unroll
    for (int mi = 0; mi < 2; ++mi) {
#pragma unroll
      for (int rg = 0; rg < 4; ++rg) {
        int tl = mi * 16 + quad * 4 + rg;
        const f32x4* br = (const f32x4*)(Bms + tl * BMST);
        float dt = fsoftplus(acc[mi][ni][rg] + dtbv);
        float s = 0.f;
#pragma unroll
        for (int q = 0; q < 4; ++q) {
          f32x4 bq = br[q];
#pragma unroll
          for (int j = 0; j < 4; ++j) s += fexp2(av[q][j] * dt) * bq[j];
        }
        float xcv = (float)xcs[(tl + 3) * XST + d];
        float y = dt * xcv * s + dpv * xcv;
        float zf = (float)zsave[ni >> 1][mi][ni & 1][rg];
        xcs[(tl + 3) * XST + d] = (__bf16)(y * zf * fsigmoid(zf));
      }
    }
  }
  __syncthreads();  // y' complete block-wide

  // ---- P5: out-GEMM, wave owns cols [w*32,+32). 2-deep B prefetch. ----
  int wn = w * 32;
  const __bf16* oWp = oW + (size_t)(wn + l15) * DI + quad * 8;
  f32x4 oacc[2][2] = {};
  {
    bf16x8 onx0[2], onx1[2];
#pragma unroll
    for (int ni = 0; ni < 2; ++ni) {
      onx0[ni] = *(const bf16x8*)(oWp + (size_t)ni * 16 * DI);
      onx1[ni] = *(const bf16x8*)(oWp + (size_t)ni * 16 * DI + 32);
    }
#pragma unroll
    for (int kk = 0; kk < 16; ++kk) {
      int k0 = kk * 32;
      bf16x8 ocur[2];
#pragma unroll
      for (int ni = 0; ni < 2; ++ni) { ocur[ni] = onx0[ni]; onx0[ni] = onx1[ni]; }
      if (kk < 14) {
#pragma unroll
        for (int ni = 0; ni < 2; ++ni)
          onx1[ni] = *(const bf16x8*)(oWp + (size_t)ni * 16 * DI + k0 + 64);
      }
      bf16x8 af[2];
#pragma unroll
      for (int mi = 0; mi < 2; ++mi)
        af[mi] = *(const bf16x8*)(xcs + (mi * 16 + l15 + 3) * XST + k0 + quad * 8);
#pragma unroll
      for (int mi = 0; mi < 2; ++mi)
#pragma unroll
        for (int ni = 0; ni < 2; ++ni)
          oacc[mi][ni] = __builtin_amdgcn_mfma_f32_16x16x32_bf16(af[mi], ocur[ni], oacc[mi][ni], 0, 0, 0);
    }
  }
  __syncthreads();  // all xcs reads done; xcs region free for overlays

  if constexpr (!DOHEAD) {
    // ---- P6a: scatter yout into vst (f32 overlay on dead xcs) ----
    float* vst = (float*)(smem + VST_OFF);
#pragma unroll
    for (int mi = 0; mi < 2; ++mi)
#pragma unroll
      for (int ni = 0; ni < 2; ++ni)
#pragma unroll
        for (int rg = 0; rg < 4; ++rg) {
          int tl = mi * 16 + quad * 4 + rg;
          vst[tl * VST + wn + ni * 16 + l15] = oacc[mi][ni][rg];
        }
    __syncthreads();

    // ---- P6b: row-major epilogue: residual (from xbs LDS!) + rmsnorm +
    //      FULL-LINE xbout writes. ----
    int row = tid >> 4;       // 0..31
    int seg = tid & 15;
    float vv[4][4];
    float sq = 0.f;
#pragma unroll
    for (int j4 = 0; j4 < 4; ++j4) {
      int c = j4 * 64 + seg * 4;
      bf16x4 rv = *(const bf16x4*)(xbs + (16 + row) * XBST + c);
#pragma unroll
      for (int j = 0; j < 4; ++j) {
        float v = vst[row * VST + c + j] + (float)rv[j];
        vv[j4][j] = v;
        sq += v * v;
      }
    }
    sq += __shfl_xor(sq, 1);
    sq += __shfl_xor(sq, 2);
    sq += __shfl_xor(sq, 4);
    sq += __shfl_xor(sq, 8);
    float r = rsqrtf(sq * (1.f / DM) + RMS_EPS);
    __hip_bfloat16* xbw = xbout + (size_t)(t0 + row) * DM;
#pragma unroll
    for (int j4 = 0; j4 < 4; ++j4) {
      int c = j4 * 64 + seg * 4;
      f32x4 nv = *(const f32x4*)(nw + c);
      bf16x4 ob;
#pragma unroll
      for (int j = 0; j < 4; ++j)
        ob[j] = (__bf16)(vv[j4][j] * r * nv[j]);
      *(bf16x4*)(xbw + c) = ob;
    }
  } else {
    // ---- P6 (DOHEAD): column-partitioned rmsnorm (no vst; output is LDS
    //      hts so coalescing doesn't matter). Cross-wave reduce via rmsp. ----
    __bf16* hts = (__bf16*)(smem + HTS_OFF);
    float* rmsp = (float*)(smem + RMSP_OFF);   // [32][8]
    float vv[2][2][4];
#pragma unroll
    for (int mi = 0; mi < 2; ++mi) {
#pragma unroll
      for (int rg = 0; rg < 4; ++rg) {
        int tl = mi * 16 + quad * 4 + rg;
        float sqp = 0.f;
#pragma unroll
        for (int ni = 0; ni < 2; ++ni) {
          float rv = (float)xbs[(16 + tl) * XBST + wn + ni * 16 + l15];
          float v = oacc[mi][ni][rg] + rv;
          vv[mi][ni][rg] = v;
          sqp += v * v;
        }
        sqp += __shfl_xor(sqp, 1);
        sqp += __shfl_xor(sqp, 2);
        sqp += __shfl_xor(sqp, 4);
        sqp += __shfl_xor(sqp, 8);
        if (l15 == 0) rmsp[tl * 8 + w] = sqp;
      }
    }
    __syncthreads();
#pragma unroll
    for (int mi = 0; mi < 2; ++mi) {
#pragma unroll
      for (int rg = 0; rg < 4; ++rg) {
        int tl = mi * 16 + quad * 4 + rg;
        float tot = 0.f;
#pragma unroll
        for (int ww = 0; ww < 8; ++ww) tot += rmsp[tl * 8 + ww];
        float r = rsqrtf(tot * (1.f / DM) + RMS_EPS);
#pragma unroll
        for (int ni = 0; ni < 2; ++ni) {
          int c = wn + ni * 16 + l15;
          hts[tl * HST3 + c] = (__bf16)(vv[mi][ni][rg] * r * nw[c]);
        }
      }
    }
    __syncthreads();

    // ---- H: fused head-GEMM + entropy. Wave w owns vocab cols [w*32,+32). ----
    float* red = (float*)(smem + RED_OFF);  // [32][8][2], reuses dead Bms
    int wv = w * 32;
    const __bf16* hp = hW + (size_t)(wv + l15) * DM + quad * 8;
    f32x4 hacc[2][2] = {};
#pragma unroll
    for (int kk = 0; kk < 8; ++kk) {
      int k0 = kk * 32;
      bf16x8 b0 = *(const bf16x8*)(hp + k0);
      bf16x8 b1 = *(const bf16x8*)(hp + (size_t)16 * DM + k0);
      bf16x8 a0 = *(const bf16x8*)(hts + l15 * HST3 + k0 + quad * 8);
      bf16x8 a1 = *(const bf16x8*)(hts + (16 + l15) * HST3 + k0 + quad * 8);
      hacc[0][0] = __builtin_amdgcn_mfma_f32_16x16x32_bf16(a0, b0, hacc[0][0], 0, 0, 0);
      hacc[0][1] = __builtin_amdgcn_mfma_f32_16x16x32_bf16(a0, b1, hacc[0][1], 0, 0, 0);
      hacc[1][0] = __builtin_amdgcn_mfma_f32_16x16x32_bf16(a1, b0, hacc[1][0], 0, 0, 0);
      hacc[1][1] = __builtin_amdgcn_mfma_f32_16x16x32_bf16(a1, b1, hacc[1][1], 0, 0, 0);
    }
#pragma unroll
    for (int mi = 0; mi < 2; ++mi) {
#pragma unroll
      for (int rg = 0; rg < 4; ++rg) {
        float l0 = hacc[mi][0][rg], l1 = hacc[mi][1][rg];
        float e0 = fexp(l0), e1 = fexp(l1);
        float s = e0 + e1;
        float u = e0 * l0 + e1 * l1;
        s += __shfl_xor(s, 1); u += __shfl_xor(u, 1);
        s += __shfl_xor(s, 2); u += __shfl_xor(u, 2);
        s += __shfl_xor(s, 4); u += __shfl_xor(u, 4);
        s += __shfl_xor(s, 8); u += __shfl_xor(u, 8);
        if (l15 == 0) {
          int tl = mi * 16 + quad * 4 + rg;
          red[(tl * 8 + w) * 2] = s;
          red[(tl * 8 + w) * 2 + 1] = u;
        }
      }
    }
    __syncthreads();
    if (tid < 32) {
      float s = 0.f, u = 0.f;
#pragma unroll
      for (int ww = 0; ww < 8; ++ww) {
        s += red[(tid * 8 + ww) * 2];
        u += red[(tid * 8 + ww) * 2 + 1];
      }
      ent[t0 + tid] = (flog(s) - u * frcp(s)) * (1.f / LOG_VOCAB);
    }
  }
}

// ---------------------------------------------------------------------------
// Parallel boundary scan (anchors via block max-scan). BB blocks x 256 thr.
// ---------------------------------------------------------------------------
__global__ __launch_bounds__(256) void scan_kernel(
    const float* __restrict__ ent, float* __restrict__ btp_out,
    int* __restrict__ pstart, int* __restrict__ npatch) {
  __shared__ int sh[256];
  int b = blockIdx.x, t = threadIdx.x;
  int sbase = t * 8;
  f32x4 e0 = *(const f32x4*)(ent + (size_t)b * SS + sbase);
  f32x4 e1 = *(const f32x4*)(ent + (size_t)b * SS + sbase + 4);
  float e[8] = {e0[0], e0[1], e0[2], e0[3], e1[0], e1[1], e1[2], e1[3]};
  int la = -1;
  unsigned cbits = 0;
#pragma unroll
  for (int j = 0; j < 8; ++j) {
    int s = sbase + j;
    bool cb = (s == 0) || (e[j] > THR_);
    if (cb) { la = s; cbits |= 1u << j; }
  }
  sh[t] = la;
  __syncthreads();
  int run = la;
  for (int off = 1; off < 256; off <<= 1) {
    int other = (t >= off) ? sh[t - off] : -1;
    __syncthreads();
    run = max(run, other);
    sh[t] = run;
    __syncthreads();
  }
  int anchor = (t > 0) ? sh[t - 1] : -1;
  unsigned bits = 0;
#pragma unroll
  for (int j = 0; j < 8; ++j) {
    int s = sbase + j;
    bool cb = (cbits >> j) & 1u;
    bool bnd;
    if (cb) { bnd = true; anchor = s; }
    else bnd = ((s - anchor) & 7) == 0;
    bits |= (unsigned)bnd << j;
  }
  int cnt = __popc(bits);
  __syncthreads();
  sh[t] = cnt;
  __syncthreads();
  int runc = cnt;
  for (int off = 1; off < 256; off <<= 1) {
    int other = (t >= off) ? sh[t - off] : 0;
    __syncthreads();
    runc += other;
    sh[t] = runc;
    __syncthreads();
  }
  if (t == 255) npatch[b] = runc;
  int btp = (runc - cnt) - 1;
#pragma unroll
  for (int j = 0; j < 8; ++j) {
    int s = sbase + j;
    if ((bits >> j) & 1u) { ++btp; pstart[b * SS + btp] = s; }
    btp_out[b * SS + s] = (float)btp;
  }
}

// ---------------------------------------------------------------------------
// patch mean pooling: 2048 blocks, 8 patches/block, 32 threads/patch.
// ---------------------------------------------------------------------------
__global__ __launch_bounds__(256) void patch_kernel(
    const float* __restrict__ bemb, const int* __restrict__ pstart,
    const int* __restrict__ npatch, float* __restrict__ pe_out,
    float* __restrict__ plen_out) {
  int bp8 = blockIdx.x;            // 0..2047
  int b = bp8 >> 8;                // 256 blocks per batch
  int p0 = (bp8 & 255) * 8;
  int t = threadIdx.x;
  int g = t >> 5;                  // patch group 0..7
  int t32 = t & 31;
  int p = p0 + g;
  int np = npatch[b];
  size_t outbase = ((size_t)b * SS + p) * DM + t32 * 8;
  if (p >= np) {
    f32x4 z = {0.f, 0.f, 0.f, 0.f};
    *(f32x4*)(pe_out + outbase) = z;
    *(f32x4*)(pe_out + outbase + 4) = z;
    if (t32 == 0) plen_out[b * SS + p] = 0.f;
    return;
  }
  int start = pstart[b * SS + p];
  int end = (p + 1 < np) ? pstart[b * SS + p + 1] : SS;
  f32x4 a0 = {0.f, 0.f, 0.f, 0.f}, a1 = {0.f, 0.f, 0.f, 0.f};
  for (int r = start; r < end; ++r) {
    const float* row = bemb + ((size_t)b * SS + r) * DM + t32 * 8;
    f32x4 v0 = *(const f32x4*)row;
    f32x4 v1 = *(const f32x4*)(row + 4);
#pragma unroll
    for (int j = 0; j < 4; ++j) { a0[j] += v0[j]; a1[j] += v1[j]; }
  }
  float inv = frcp((float)(end - start));
#pragma unroll
  for (int j = 0; j < 4; ++j) { a0[j] *= inv; a1[j] *= inv; }
  *(f32x4*)(pe_out + outbase) = a0;
  *(f32x4*)(pe_out + outbase + 4) = a1;
  if (t32 == 0) plen_out[b * SS + p] = (float)(end - start);
}

// ---------------------------------------------------------------------------
// Launcher — 5 dispatches total
// ---------------------------------------------------------------------------
extern "C" void kernel_launch(void* const* d_in, const int* in_sizes, int n_in,
                              void* d_out, int out_size, void* d_ws, size_t ws_size,
                              hipStream_t stream) {
  const int* bytes = (const int*)d_in[0];
  const float* bemb = (const float*)d_in[1];
  const float* embed_w = (const float*)d_in[2];
  const float* in_proj_w = (const float*)d_in[3];
  const float* conv_w = (const float*)d_in[4];
  const float* conv_b = (const float*)d_in[5];
  const float* x_proj_w = (const float*)d_in[6];
  const float* dt_w = (const float*)d_in[7];
  const float* dt_b = (const float*)d_in[8];
  const float* A_log = (const float*)d_in[9];
  const float* D_param = (const float*)d_in[10];
  const float* out_w = (const float*)d_in[11];
  const float* norm_w = (const float*)d_in[12];
  const float* head_w = (const float*)d_in[13];

  float* out = (float*)d_out;
  float* pe_out = out;                      // (B,S,DM)
  float* plen_out = out + (size_t)TT * DM;  // (B,S)
  float* btp_out = plen_out + TT;           // (B,S)

  char* wsb = (char*)d_ws;
  size_t off = 0;
  auto alloc = [&](size_t bytes_) -> void* {
    void* p = wsb + off;
    off += (bytes_ + 255) & ~(size_t)255;
    return p;
  };
  float* A2 = (float*)alloc((size_t)NLAYERS * DI * DSTATE * 4);
  __hip_bfloat16* xb0 = (__hip_bfloat16*)alloc((size_t)TT * DM * 2);
  __hip_bfloat16* xb1 = (__hip_bfloat16*)alloc((size_t)TT * DM * 2);
  float* ent = (float*)alloc((size_t)TT * 4);
  int* pstart = (int*)alloc((size_t)TT * 4);
  int* npatch = (int*)alloc(256);
  __hip_bfloat16* inWt = (__hip_bfloat16*)alloc((size_t)NLAYERS * 2 * DI * DM * 2);
  __hip_bfloat16* dtWt = (__hip_bfloat16*)alloc((size_t)NLAYERS * DI * DI * 2);
  __hip_bfloat16* oWt = (__hip_bfloat16*)alloc((size_t)NLAYERS * DM * DI * 2);
  __hip_bfloat16* xpWt = (__hip_bfloat16*)alloc((size_t)NLAYERS * 32 * DI * 2);
  __hip_bfloat16* headWt = (__hip_bfloat16*)alloc((size_t)VOCAB * DM * 2);

  // 1: weight transposes + A2 + embedding (merged; xb only, no f32 x)
  prep_wtrans<<<PW_BLOCKS, 256, 0, stream>>>(
      in_proj_w, inWt, dt_w, dtWt, out_w, oWt, head_w, headWt,
      x_proj_w, xpWt, A_log, A2, bytes, embed_w, xb0);

  // 2: Mamba layer 0 (writes xb1 only)
  size_t fused_lds = (size_t)XBS_BYTES + (size_t)35 * XST * 2 + (size_t)TW * BMST * 4;
  mamba_fused<false><<<TT / TW, 512, fused_lds, stream>>>(
      xb0, xb1,
      (const __bf16*)inWt, (const __bf16*)dtWt, (const __bf16*)oWt,
      (const __bf16*)xpWt,
      conv_w, conv_b, A2, dt_b, D_param, norm_w, nullptr, nullptr);

  // 3: Mamba layer 1 + fused head-GEMM + entropy (writes ent only)
  mamba_fused<true><<<TT / TW, 512, fused_lds, stream>>>(
      xb1, xb0,
      (const __bf16*)(inWt + (size_t)1 * 2 * DI * DM),
      (const __bf16*)(dtWt + (size_t)1 * DI * DI),
      (const __bf16*)(oWt + (size_t)1 * DM * DI),
      (const __bf16*)(xpWt + (size_t)1 * 32 * DI),
      conv_w + (size_t)1 * DI * DCONV, conv_b + (size_t)1 * DI,
      A2 + (size_t)1 * DI * DSTATE, dt_b + (size_t)1 * DI,
      D_param + (size_t)1 * DI, norm_w + (size_t)1 * DM,
      (const __bf16*)headWt, ent);

  // 4: boundary scan (parallel)
  scan_kernel<<<BB, 256, 0, stream>>>(ent, btp_out, pstart, npatch);

  // 5: patch mean pooling (8 patches/block)
  patch_kernel<<<TT / 8, 256, 0, stream>>>(bemb, pstart, npatch, pe_out, plen_out);
}

// Round 15
// 223.203 us; speedup vs baseline: 2.0493x; 1.3520x over previous
//
#include <hip/hip_runtime.h>
#include <hip/hip_bf16.h>
#include <math.h>

// Problem constants
#define BB 8
#define SS 2048
#define TT (BB * SS)      // 16384 tokens
#define DM 256
#define DI 512
#define DSTATE 16
#define DCONV 4
#define NLAYERS 2
#define VOCAB 256
#define LOG_VOCAB 5.545177444479562f
#define RMS_EPS 1.1920929e-07f
#define LOG2E 1.4426950408889634f
#define LN2 0.6931471805599453f
#define THR_ 0.5f

#define TW 32            // tokens per fused block: grid 512 -> 2 blocks/CU
#define XBST 264         // xbs (A-tile) LDS row stride (bf16): 528B -> 2-way aliasing only
#define XST 520          // xcs LDS row stride (bf16 elems): 1040B -> 2-way bank aliasing only
#define BMST 20          // Bms LDS row stride (f32)
#define VST 260          // vst (f32 epilogue overlay) row stride
#define HST3 264         // hts (head A-tile) row stride (bf16)
// LDS layout: xbs [0,25344) | xcs [25344,61744) | Bms [61744,64304)
#define XBS_BYTES 25344
#define VST_OFF 25344
#define HTS_OFF 25344
#define RMSP_OFF 42240
#define RED_OFF 61744

typedef __attribute__((ext_vector_type(8))) __bf16 bf16x8;
typedef __attribute__((ext_vector_type(4))) __bf16 bf16x4;
typedef __attribute__((ext_vector_type(2))) __bf16 bf16x2;
typedef __attribute__((ext_vector_type(4))) float f32x4;

// ---- fast transcendentals (1-ulp class; entropy margin vs THR=0.5 is ~0.4) ----
__device__ __forceinline__ float fexp(float x) { return __builtin_amdgcn_exp2f(x * LOG2E); }
__device__ __forceinline__ float fexp2(float x) { return __builtin_amdgcn_exp2f(x); }
__device__ __forceinline__ float flog(float x) { return __builtin_amdgcn_logf(x) * LN2; }
__device__ __forceinline__ float frcp(float x) { return __builtin_amdgcn_rcpf(x); }
__device__ __forceinline__ float fsigmoid(float x) { return frcp(1.f + fexp(-x)); }
__device__ __forceinline__ float fsoftplus(float x) {
  return fmaxf(x, 0.f) + flog(1.f + fexp(-fabsf(x)));
}

// ---------------------------------------------------------------------------
// Fragment-packed weight layout. The MFMA B-fragment for (row-tile R=n/16,
// k-tile C=k/32) is 64 lanes x 16B (lane = quad*16 + l15 reads row
// R*16+l15, cols C*32+quad*8..+8). pkidx places each fragment as one
// CONTIGUOUS 1KB block: in-kernel weight loads become base + frag*512 +
// lane*8 -> zero address divergence (the old [N][K] layout gathered every
// load instruction across 16 cache lines at 1KB stride -> memory-pipe
// serialization; rocprof: 64% of mamba cycles neither VALU nor MFMA).
// ---------------------------------------------------------------------------
__device__ __forceinline__ size_t pkidx(int n, int k, int K) {
  return ((size_t)(n >> 4) * (K >> 5) + (k >> 5)) * 512 +
         ((((k >> 3) & 3) * 16 + (n & 15)) * 8) + (k & 7);
}

// ---------------------------------------------------------------------------
// prep_wtrans: merged weight transposes->PACKED (bid<352) + A2/embedding.
// ---------------------------------------------------------------------------
#define PREP_V4 (4096 + TT * DM / 4)
#define WT_BLOCKS 352
#define PW_BLOCKS (WT_BLOCKS + (PREP_V4 + 255) / 256)

__global__ __launch_bounds__(256) void prep_wtrans(
    const float* __restrict__ in_proj_w, __hip_bfloat16* __restrict__ inWt,
    const float* __restrict__ dt_w, __hip_bfloat16* __restrict__ dtWt,
    const float* __restrict__ out_w, __hip_bfloat16* __restrict__ oWt,
    const float* __restrict__ head_w, __hip_bfloat16* __restrict__ headWt,
    const float* __restrict__ x_proj_w, __hip_bfloat16* __restrict__ xpWt,
    const float* __restrict__ A_log, float* __restrict__ A2,
    const int* __restrict__ bytes, const float* __restrict__ embed_w,
    __hip_bfloat16* __restrict__ xb) {
  __shared__ float tile[64][65];
  int bid = blockIdx.x;
  int tid = threadIdx.x;
  if (bid >= WT_BLOCKS) {  // ---- prep path ----
    int i = (bid - WT_BLOCKS) * 256 + tid;
    if (i >= PREP_V4) return;
    if (i < 4096) {
      f32x4 a = *(const f32x4*)(A_log + i * 4);
      f32x4 o;
#pragma unroll
      for (int j = 0; j < 4; ++j) o[j] = -fexp(a[j]) * LOG2E;
      *(f32x4*)(A2 + i * 4) = o;
      return;
    }
    i -= 4096;
    int t = i >> 6;
    int c4 = (i & 63) * 4;
    f32x4 v = *(const f32x4*)(embed_w + (size_t)bytes[t] * DM + c4);
    bf16x4 ob;
#pragma unroll
    for (int j = 0; j < 4; ++j) ob[j] = (__bf16)v[j];
    *(bf16x4*)((__bf16*)xb + (size_t)t * DM + c4) = ob;
    return;
  }
  // ---- wtrans path (transpose f32 [K][N] -> packed bf16 W^T fragments) ----
  const float* src;
  __hip_bfloat16* dst;
  int K, N, kt, nt, nw = 64;
  if (bid < 128) {        // in_proj: [256][1024] -> [1024][256] packed
    int l = bid >> 6, r = bid & 63;
    src = in_proj_w + (size_t)l * 262144; dst = inWt + (size_t)l * 262144;
    K = 256; N = 1024; kt = r >> 4; nt = r & 15;
  } else if (bid < 256) { // dt: [512][512] -> [512][512] packed
    int i = bid - 128; int l = i >> 6, r = i & 63;
    src = dt_w + (size_t)l * 262144; dst = dtWt + (size_t)l * 262144;
    K = 512; N = 512; kt = r >> 3; nt = r & 7;
  } else if (bid < 320) { // out: [512][256] -> [256][512] packed
    int i = bid - 256; int l = i >> 5, r = i & 31;
    src = out_w + (size_t)l * 131072; dst = oWt + (size_t)l * 131072;
    K = 512; N = 256; kt = r >> 2; nt = r & 3;
  } else if (bid < 336) { // head: [256][256] -> [256][256] packed
    int r = bid - 320;
    src = head_w; dst = headWt;
    K = 256; N = 256; kt = r >> 2; nt = r & 3;
  } else {                // x_proj: [512][32] -> [32][512] packed (64x32 tiles)
    int i = bid - 336; int l = i >> 3, r = i & 7;
    src = x_proj_w + (size_t)l * 16384; dst = xpWt + (size_t)l * 16384;
    K = 512; N = 32; kt = r; nt = 0; nw = 32;
  }
  int k0 = kt * 64, n0 = nt * 64;
  if (nw == 64) {
    int r0 = tid >> 4, c4 = (tid & 15) * 4;
#pragma unroll
    for (int rr = 0; rr < 4; ++rr) {
      int r = rr * 16 + r0;
      f32x4 v = *(const f32x4*)(src + (size_t)(k0 + r) * N + n0 + c4);
      tile[r][c4] = v[0]; tile[r][c4 + 1] = v[1]; tile[r][c4 + 2] = v[2]; tile[r][c4 + 3] = v[3];
    }
    __syncthreads();
    int n = tid >> 2, kc = (tid & 3) * 16;
#pragma unroll
    for (int cc = 0; cc < 2; ++cc) {
      int k = kc + cc * 8;
      bf16x8 o;
#pragma unroll
      for (int j = 0; j < 8; ++j) o[j] = (__bf16)tile[k + j][n];
      *(bf16x8*)((__bf16*)dst + pkidx(n0 + n, k0 + k, K)) = o;
    }
  } else {
    int r0 = tid >> 3, c4 = (tid & 7) * 4;
#pragma unroll
    for (int rr = 0; rr < 2; ++rr) {
      int r = rr * 32 + r0;
      f32x4 v = *(const f32x4*)(src + (size_t)(k0 + r) * N + c4);
      tile[r][c4] = v[0]; tile[r][c4 + 1] = v[1]; tile[r][c4 + 2] = v[2]; tile[r][c4 + 3] = v[3];
    }
    __syncthreads();
    int n = tid >> 3, kc = (tid & 7) * 8;
    bf16x8 o;
#pragma unroll
    for (int j = 0; j < 8; ++j) o[j] = (__bf16)tile[kc + j][n];
    *(bf16x8*)((__bf16*)dst + pkidx(n, k0 + kc, K)) = o;
  }
}

// ---------------------------------------------------------------------------
// Fully-fused Mamba layer (round-13 body) with FRAGMENT-PACKED weight loads:
// every B-operand load is now base + frag*512 + lane*8 (contiguous 1KB per
// wave-instruction). A-side (xcs/xbs LDS) and all math unchanged ->
// bit-identical results. KC(inW/hW)=8, KC(dtW/oW/xpW)=16 fragments per row-tile.
// ---------------------------------------------------------------------------
template <bool DOHEAD>
__global__ __launch_bounds__(512, 4) void mamba_fused(
    const __hip_bfloat16* __restrict__ xbin,  // [TT][256] layer input (bf16)
    __hip_bfloat16* __restrict__ xbout,       // [TT][256] layer output (bf16)
    const __bf16* __restrict__ inW,           // packed [1024][256]
    const __bf16* __restrict__ dtW,           // packed [512][512]
    const __bf16* __restrict__ oW,            // packed [256][512]
    const __bf16* __restrict__ xpW,           // packed [32][512] (rows 0..15 = B)
    const float* __restrict__ cw, const float* __restrict__ cb,
    const float* __restrict__ A2, const float* __restrict__ dtb,
    const float* __restrict__ Dp, const float* __restrict__ nw,
    const __bf16* __restrict__ hW, float* __restrict__ ent) {
  extern __shared__ char smem[];
  __bf16* xbs = (__bf16*)smem;                       // [48][XBST], live to end
  __bf16* xcs = (__bf16*)(smem + XBS_BYTES);         // [35][XST]: xin -> xc -> y'
  float* Bms = (float*)(smem + XBS_BYTES + 35 * XST * 2);  // [32][BMST]

  int tid = threadIdx.x;
  int lane = tid & 63;
  int w = tid >> 6;          // 8 waves
  int quad = lane >> 4;
  int l15 = lane & 15;
  int t0 = blockIdx.x * TW;
  int s0 = t0 & (SS - 1);

  // ---- S: stage A-tile xb[t0-16 .. t0+31] -> xbs (48x256, coalesced) ----
#pragma unroll
  for (int it = 0; it < 3; ++it) {
    int idx = it * 512 + tid;
    int r = idx >> 5, c8 = (idx & 31) * 8;
    int tok = t0 - 16 + r;
    if (tok < 0) tok = 0;  // only block 0; halo unused there (s0==0)
    *(bf16x8*)(xbs + r * XBST + c8) =
        *(const bf16x8*)((const __bf16*)xbin + (size_t)tok * DM + c8);
  }
  __syncthreads();

  // ---- G1: x_in = xbtile @ inW^T cols [w*64,+64), packed B, 2-deep. ----
  int wn64 = w * 64;
#pragma unroll 1
  for (int cth = 0; cth < 2; ++cth) {
    const __bf16* bp[2];
#pragma unroll
    for (int ni = 0; ni < 2; ++ni)
      bp[ni] = inW + (size_t)(w * 4 + cth * 2 + ni) * 8 * 512 + lane * 8;
    f32x4 ga[3][2] = {};
    bf16x8 bnx0[2], bnx1[2];
#pragma unroll
    for (int ni = 0; ni < 2; ++ni) {
      bnx0[ni] = *(const bf16x8*)(bp[ni]);
      bnx1[ni] = *(const bf16x8*)(bp[ni] + 512);
    }
#pragma unroll
    for (int kk = 0; kk < 8; ++kk) {
      int k0 = kk * 32;
      bf16x8 bcur[2];
#pragma unroll
      for (int ni = 0; ni < 2; ++ni) { bcur[ni] = bnx0[ni]; bnx0[ni] = bnx1[ni]; }
      if (kk < 6) {
#pragma unroll
        for (int ni = 0; ni < 2; ++ni)
          bnx1[ni] = *(const bf16x8*)(bp[ni] + (size_t)(kk + 2) * 512);
      }
      bf16x8 af[3];
#pragma unroll
      for (int rt = 0; rt < 3; ++rt)
        af[rt] = *(const bf16x8*)(xbs + (rt * 16 + l15) * XBST + k0 + quad * 8);
#pragma unroll
      for (int rt = 0; rt < 3; ++rt)
#pragma unroll
        for (int ni = 0; ni < 2; ++ni)
          ga[rt][ni] = __builtin_amdgcn_mfma_f32_16x16x32_bf16(af[rt], bcur[ni], ga[rt][ni], 0, 0, 0);
    }
#pragma unroll
    for (int rt = 0; rt < 3; ++rt)
#pragma unroll
      for (int ni = 0; ni < 2; ++ni)
#pragma unroll
        for (int rg = 0; rg < 4; ++rg) {
          int grow = rt * 16 + quad * 4 + rg;
          if (grow >= 13)
            xcs[(grow - 13) * XST + wn64 + cth * 32 + ni * 16 + l15] = (__bf16)ga[rt][ni][rg];
        }
  }
  __syncthreads();  // xin complete in LDS (conv reads all cols)

  // ---- P0: conv+silu IN-PLACE on xcs (halo rows 0..2, tokens rows 3..34) ----
  {
    int d = tid;
    float wv[4];
#pragma unroll
    for (int k = 0; k < 4; ++k) wv[k] = cw[d * 4 + k];
    float b = cb[d];
    float h0 = 0, h1 = 0, h2 = 0;
    if (s0 > 0) {
      h0 = (float)xcs[0 * XST + d];
      h1 = (float)xcs[1 * XST + d];
      h2 = (float)xcs[2 * XST + d];
    }
#pragma unroll 4
    for (int s = 0; s < TW; ++s) {
      float c = (float)xcs[(s + 3) * XST + d];
      float a = b + wv[0] * h0 + wv[1] * h1 + wv[2] * h2 + wv[3] * c;
      xcs[(s + 3) * XST + d] = (__bf16)(a * fsigmoid(a));
      h0 = h1; h1 = h2; h2 = c;
    }
  }
  __syncthreads();

  // ---- P1: Bmat = xc @ xpW^T (waves 0-1; packed xpW rows 0..15 = R0) ----
  if (w < 2) {
    f32x4 bacc = {};
#pragma unroll
    for (int kk = 0; kk < 16; ++kk) {
      bf16x8 a = *(const bf16x8*)(xcs + (w * 16 + l15 + 3) * XST + kk * 32 + quad * 8);
      bf16x8 bb = *(const bf16x8*)(xpW + (size_t)kk * 512 + lane * 8);
      bacc = __builtin_amdgcn_mfma_f32_16x16x32_bf16(a, bb, bacc, 0, 0, 0);
    }
#pragma unroll
    for (int rg = 0; rg < 4; ++rg)
      Bms[(w * 16 + quad * 4 + rg) * BMST + l15] = bacc[rg];
  }

  // ---- P2: dt-GEMM, wave owns channels [w*64,+64). Packed B, 2-deep. ----
  int dbase = w * 64;
  f32x4 acc[2][4] = {};
  {
    const __bf16* dtp[4];
#pragma unroll
    for (int ni = 0; ni < 4; ++ni)
      dtp[ni] = dtW + (size_t)(w * 4 + ni) * 16 * 512 + lane * 8;
    bf16x8 bnx0[4], bnx1[4];
#pragma unroll
    for (int ni = 0; ni < 4; ++ni) {
      bnx0[ni] = *(const bf16x8*)(dtp[ni]);
      bnx1[ni] = *(const bf16x8*)(dtp[ni] + 512);
    }
#pragma unroll
    for (int kk = 0; kk < 16; ++kk) {
      int k0 = kk * 32;
      bf16x8 bcur[4];
#pragma unroll
      for (int ni = 0; ni < 4; ++ni) { bcur[ni] = bnx0[ni]; bnx0[ni] = bnx1[ni]; }
      if (kk < 14) {
#pragma unroll
        for (int ni = 0; ni < 4; ++ni)
          bnx1[ni] = *(const bf16x8*)(dtp[ni] + (size_t)(kk + 2) * 512);
      }
      bf16x8 af[2];
#pragma unroll
      for (int mi = 0; mi < 2; ++mi)
        af[mi] = *(const bf16x8*)(xcs + (mi * 16 + l15 + 3) * XST + k0 + quad * 8);
#pragma unroll
      for (int mi = 0; mi < 2; ++mi)
#pragma unroll
        for (int ni = 0; ni < 4; ++ni)
          acc[mi][ni] = __builtin_amdgcn_mfma_f32_16x16x32_bf16(af[mi], bcur[ni], acc[mi][ni], 0, 0, 0);
    }
  }

  // ---- G2: z = xbtile @ inW^T cols [512+w*64,+64) -> REGISTERS. Packed. ----
  bf16x4 zsave[2][2][2];
#pragma unroll
  for (int cth = 0; cth < 2; ++cth) {
    const __bf16* bp[2];
#pragma unroll
    for (int ni = 0; ni < 2; ++ni)
      bp[ni] = inW + (size_t)(32 + w * 4 + cth * 2 + ni) * 8 * 512 + lane * 8;
    f32x4 gz[2][2] = {};
    bf16x8 bnx0[2], bnx1[2];
#pragma unroll
    for (int ni = 0; ni < 2; ++ni) {
      bnx0[ni] = *(const bf16x8*)(bp[ni]);
      bnx1[ni] = *(const bf16x8*)(bp[ni] + 512);
    }
#pragma unroll
    for (int kk = 0; kk < 8; ++kk) {
      int k0 = kk * 32;
      bf16x8 bcur[2];
#pragma unroll
      for (int ni = 0; ni < 2; ++ni) { bcur[ni] = bnx0[ni]; bnx0[ni] = bnx1[ni]; }
      if (kk < 6) {
#pragma unroll
        for (int ni = 0; ni < 2; ++ni)
          bnx1[ni] = *(const bf16x8*)(bp[ni] + (size_t)(kk + 2) * 512);
      }
      bf16x8 af[2];
#pragma unroll
      for (int rt = 0; rt < 2; ++rt)
        af[rt] = *(const bf16x8*)(xbs + ((16 + rt * 16) + l15) * XBST + k0 + quad * 8);
#pragma unroll
      for (int rt = 0; rt < 2; ++rt)
#pragma unroll
        for (int ni = 0; ni < 2; ++ni)
          gz[rt][ni] = __builtin_amdgcn_mfma_f32_16x16x32_bf16(af[rt], bcur[ni], gz[rt][ni], 0, 0, 0);
    }
#pragma unroll
    for (int rt = 0; rt < 2; ++rt)
#pragma unroll
      for (int ni = 0; ni < 2; ++ni)
#pragma unroll
        for (int rg = 0; rg < 4; ++rg)
          zsave[cth][rt][ni][rg] = (__bf16)gz[rt][ni][rg];
  }
  __syncthreads();  // Bms visible; all full-width xcs reads (P1/P2) done

  // ---- P2b: ssm in-register + fold silu(z) from zsave; write y' to own slab ----
#pragma unroll
  for (int ni = 0; ni < 4; ++ni) {
    int d = dbase + ni * 16 + l15;
    float dtbv = dtb[d];
    float dpv = Dp[d];
    const f32x4* ar = (const f32x4*)(A2 + d * DSTATE);
    f32x4 av[4];
#pragma unroll
    for (int q = 0; q < 4; ++q) av[q] = ar[q];
#pragma unroll
    for (int mi = 0; mi < 2; ++mi) {
#pragma unroll
      for (int rg = 0; rg < 4; ++rg) {
        int tl = mi * 16 + quad * 4 + rg;
        const f32x4* br = (const f32x4*)(Bms + tl * BMST);
        float dt = fsoftplus(acc[mi][ni][rg] + dtbv);
        float s = 0.f;
#pragma unroll
        for (int q = 0; q < 4; ++q) {
          f32x4 bq = br[q];
#pragma unroll
          for (int j = 0; j < 4; ++j) s += fexp2(av[q][j] * dt) * bq[j];
        }
        float xcv = (float)xcs[(tl + 3) * XST + d];
        float y = dt * xcv * s + dpv * xcv;
        float zf = (float)zsave[ni >> 1][mi][ni & 1][rg];
        xcs[(tl + 3) * XST + d] = (__bf16)(y * zf * fsigmoid(zf));
      }
    }
  }
  __syncthreads();  // y' complete block-wide

  // ---- P5: out-GEMM, wave owns cols [w*32,+32). Packed B, 2-deep. ----
  int wn = w * 32;
  f32x4 oacc[2][2] = {};
  {
    const __bf16* op[2];
#pragma unroll
    for (int ni = 0; ni < 2; ++ni)
      op[ni] = oW + (size_t)(w * 2 + ni) * 16 * 512 + lane * 8;
    bf16x8 onx0[2], onx1[2];
#pragma unroll
    for (int ni = 0; ni < 2; ++ni) {
      onx0[ni] = *(const bf16x8*)(op[ni]);
      onx1[ni] = *(const bf16x8*)(op[ni] + 512);
    }
#pragma unroll
    for (int kk = 0; kk < 16; ++kk) {
      int k0 = kk * 32;
      bf16x8 ocur[2];
#pragma unroll
      for (int ni = 0; ni < 2; ++ni) { ocur[ni] = onx0[ni]; onx0[ni] = onx1[ni]; }
      if (kk < 14) {
#pragma unroll
        for (int ni = 0; ni < 2; ++ni)
          onx1[ni] = *(const bf16x8*)(op[ni] + (size_t)(kk + 2) * 512);
      }
      bf16x8 af[2];
#pragma unroll
      for (int mi = 0; mi < 2; ++mi)
        af[mi] = *(const bf16x8*)(xcs + (mi * 16 + l15 + 3) * XST + k0 + quad * 8);
#pragma unroll
      for (int mi = 0; mi < 2; ++mi)
#pragma unroll
        for (int ni = 0; ni < 2; ++ni)
          oacc[mi][ni] = __builtin_amdgcn_mfma_f32_16x16x32_bf16(af[mi], ocur[ni], oacc[mi][ni], 0, 0, 0);
    }
  }
  __syncthreads();  // all xcs reads done; xcs region free for overlays

  if constexpr (!DOHEAD) {
    // ---- P6a: scatter yout into vst (f32 overlay on dead xcs) ----
    float* vst = (float*)(smem + VST_OFF);
#pragma unroll
    for (int mi = 0; mi < 2; ++mi)
#pragma unroll
      for (int ni = 0; ni < 2; ++ni)
#pragma unroll
        for (int rg = 0; rg < 4; ++rg) {
          int tl = mi * 16 + quad * 4 + rg;
          vst[tl * VST + wn + ni * 16 + l15] = oacc[mi][ni][rg];
        }
    __syncthreads();

    // ---- P6b: row-major epilogue: residual (from xbs LDS) + rmsnorm +
    //      FULL-LINE xbout writes. ----
    int row = tid >> 4;       // 0..31
    int seg = tid & 15;
    float vv[4][4];
    float sq = 0.f;
#pragma unroll
    for (int j4 = 0; j4 < 4; ++j4) {
      int c = j4 * 64 + seg * 4;
      bf16x4 rv = *(const bf16x4*)(xbs + (16 + row) * XBST + c);
#pragma unroll
      for (int j = 0; j < 4; ++j) {
        float v = vst[row * VST + c + j] + (float)rv[j];
        vv[j4][j] = v;
        sq += v * v;
      }
    }
    sq += __shfl_xor(sq, 1);
    sq += __shfl_xor(sq, 2);
    sq += __shfl_xor(sq, 4);
    sq += __shfl_xor(sq, 8);
    float r = rsqrtf(sq * (1.f / DM) + RMS_EPS);
    __hip_bfloat16* xbw = xbout + (size_t)(t0 + row) * DM;
#pragma unroll
    for (int j4 = 0; j4 < 4; ++j4) {
      int c = j4 * 64 + seg * 4;
      f32x4 nv = *(const f32x4*)(nw + c);
      bf16x4 ob;
#pragma unroll
      for (int j = 0; j < 4; ++j)
        ob[j] = (__bf16)(vv[j4][j] * r * nv[j]);
      *(bf16x4*)(xbw + c) = ob;
    }
  } else {
    // ---- P6 (DOHEAD): column-partitioned rmsnorm -> LDS hts. ----
    __bf16* hts = (__bf16*)(smem + HTS_OFF);
    float* rmsp = (float*)(smem + RMSP_OFF);   // [32][8]
    float vv[2][2][4];
#pragma unroll
    for (int mi = 0; mi < 2; ++mi) {
#pragma unroll
      for (int rg = 0; rg < 4; ++rg) {
        int tl = mi * 16 + quad * 4 + rg;
        float sqp = 0.f;
#pragma unroll
        for (int ni = 0; ni < 2; ++ni) {
          float rv = (float)xbs[(16 + tl) * XBST + wn + ni * 16 + l15];
          float v = oacc[mi][ni][rg] + rv;
          vv[mi][ni][rg] = v;
          sqp += v * v;
        }
        sqp += __shfl_xor(sqp, 1);
        sqp += __shfl_xor(sqp, 2);
        sqp += __shfl_xor(sqp, 4);
        sqp += __shfl_xor(sqp, 8);
        if (l15 == 0) rmsp[tl * 8 + w] = sqp;
      }
    }
    __syncthreads();
#pragma unroll
    for (int mi = 0; mi < 2; ++mi) {
#pragma unroll
      for (int rg = 0; rg < 4; ++rg) {
        int tl = mi * 16 + quad * 4 + rg;
        float tot = 0.f;
#pragma unroll
        for (int ww = 0; ww < 8; ++ww) tot += rmsp[tl * 8 + ww];
        float r = rsqrtf(tot * (1.f / DM) + RMS_EPS);
#pragma unroll
        for (int ni = 0; ni < 2; ++ni) {
          int c = wn + ni * 16 + l15;
          hts[tl * HST3 + c] = (__bf16)(vv[mi][ni][rg] * r * nw[c]);
        }
      }
    }
    __syncthreads();

    // ---- H: fused head-GEMM + entropy. Packed hW (KC=8). ----
    float* red = (float*)(smem + RED_OFF);  // [32][8][2], reuses dead Bms
    int wv = w * 32;
    f32x4 hacc[2][2] = {};
#pragma unroll
    for (int kk = 0; kk < 8; ++kk) {
      int k0 = kk * 32;
      bf16x8 b0 = *(const bf16x8*)(hW + ((size_t)(w * 2) * 8 + kk) * 512 + lane * 8);
      bf16x8 b1 = *(const bf16x8*)(hW + ((size_t)(w * 2 + 1) * 8 + kk) * 512 + lane * 8);
      bf16x8 a0 = *(const bf16x8*)(hts + l15 * HST3 + k0 + quad * 8);
      bf16x8 a1 = *(const bf16x8*)(hts + (16 + l15) * HST3 + k0 + quad * 8);
      hacc[0][0] = __builtin_amdgcn_mfma_f32_16x16x32_bf16(a0, b0, hacc[0][0], 0, 0, 0);
      hacc[0][1] = __builtin_amdgcn_mfma_f32_16x16x32_bf16(a0, b1, hacc[0][1], 0, 0, 0);
      hacc[1][0] = __builtin_amdgcn_mfma_f32_16x16x32_bf16(a1, b0, hacc[1][0], 0, 0, 0);
      hacc[1][1] = __builtin_amdgcn_mfma_f32_16x16x32_bf16(a1, b1, hacc[1][1], 0, 0, 0);
    }
#pragma unroll
    for (int mi = 0; mi < 2; ++mi) {
#pragma unroll
      for (int rg = 0; rg < 4; ++rg) {
        float l0 = hacc[mi][0][rg], l1 = hacc[mi][1][rg];
        float e0 = fexp(l0), e1 = fexp(l1);
        float s = e0 + e1;
        float u = e0 * l0 + e1 * l1;
        s += __shfl_xor(s, 1); u += __shfl_xor(u, 1);
        s += __shfl_xor(s, 2); u += __shfl_xor(u, 2);
        s += __shfl_xor(s, 4); u += __shfl_xor(u, 4);
        s += __shfl_xor(s, 8); u += __shfl_xor(u, 8);
        if (l15 == 0) {
          int tl = mi * 16 + quad * 4 + rg;
          red[(tl * 8 + w) * 2] = s;
          red[(tl * 8 + w) * 2 + 1] = u;
        }
      }
    }
    __syncthreads();
    if (tid < 32) {
      float s = 0.f, u = 0.f;
#pragma unroll
      for (int ww = 0; ww < 8; ++ww) {
        s += red[(tid * 8 + ww) * 2];
        u += red[(tid * 8 + ww) * 2 + 1];
      }
      ent[t0 + tid] = (flog(s) - u * frcp(s)) * (1.f / LOG_VOCAB);
    }
  }
}

// ---------------------------------------------------------------------------
// Parallel boundary scan (anchors via block max-scan). BB blocks x 256 thr.
// ---------------------------------------------------------------------------
__global__ __launch_bounds__(256) void scan_kernel(
    const float* __restrict__ ent, float* __restrict__ btp_out,
    int* __restrict__ pstart, int* __restrict__ npatch) {
  __shared__ int sh[256];
  int b = blockIdx.x, t = threadIdx.x;
  int sbase = t * 8;
  f32x4 e0 = *(const f32x4*)(ent + (size_t)b * SS + sbase);
  f32x4 e1 = *(const f32x4*)(ent + (size_t)b * SS + sbase + 4);
  float e[8] = {e0[0], e0[1], e0[2], e0[3], e1[0], e1[1], e1[2], e1[3]};
  int la = -1;
  unsigned cbits = 0;
#pragma unroll
  for (int j = 0; j < 8; ++j) {
    int s = sbase + j;
    bool cb = (s == 0) || (e[j] > THR_);
    if (cb) { la = s; cbits |= 1u << j; }
  }
  sh[t] = la;
  __syncthreads();
  int run = la;
  for (int off = 1; off < 256; off <<= 1) {
    int other = (t >= off) ? sh[t - off] : -1;
    __syncthreads();
    run = max(run, other);
    sh[t] = run;
    __syncthreads();
  }
  int anchor = (t > 0) ? sh[t - 1] : -1;
  unsigned bits = 0;
#pragma unroll
  for (int j = 0; j < 8; ++j) {
    int s = sbase + j;
    bool cb = (cbits >> j) & 1u;
    bool bnd;
    if (cb) { bnd = true; anchor = s; }
    else bnd = ((s - anchor) & 7) == 0;
    bits |= (unsigned)bnd << j;
  }
  int cnt = __popc(bits);
  __syncthreads();
  sh[t] = cnt;
  __syncthreads();
  int runc = cnt;
  for (int off = 1; off < 256; off <<= 1) {
    int other = (t >= off) ? sh[t - off] : 0;
    __syncthreads();
    runc += other;
    sh[t] = runc;
    __syncthreads();
  }
  if (t == 255) npatch[b] = runc;
  int btp = (runc - cnt) - 1;
#pragma unroll
  for (int j = 0; j < 8; ++j) {
    int s = sbase + j;
    if ((bits >> j) & 1u) { ++btp; pstart[b * SS + btp] = s; }
    btp_out[b * SS + s] = (float)btp;
  }
}

// ---------------------------------------------------------------------------
// patch mean pooling: 2048 blocks, 8 patches/block, 32 threads/patch.
// ---------------------------------------------------------------------------
__global__ __launch_bounds__(256) void patch_kernel(
    const float* __restrict__ bemb, const int* __restrict__ pstart,
    const int* __restrict__ npatch, float* __restrict__ pe_out,
    float* __restrict__ plen_out) {
  int bp8 = blockIdx.x;            // 0..2047
  int b = bp8 >> 8;                // 256 blocks per batch
  int p0 = (bp8 & 255) * 8;
  int t = threadIdx.x;
  int g = t >> 5;                  // patch group 0..7
  int t32 = t & 31;
  int p = p0 + g;
  int np = npatch[b];
  size_t outbase = ((size_t)b * SS + p) * DM + t32 * 8;
  if (p >= np) {
    f32x4 z = {0.f, 0.f, 0.f, 0.f};
    *(f32x4*)(pe_out + outbase) = z;
    *(f32x4*)(pe_out + outbase + 4) = z;
    if (t32 == 0) plen_out[b * SS + p] = 0.f;
    return;
  }
  int start = pstart[b * SS + p];
  int end = (p + 1 < np) ? pstart[b * SS + p + 1] : SS;
  f32x4 a0 = {0.f, 0.f, 0.f, 0.f}, a1 = {0.f, 0.f, 0.f, 0.f};
  for (int r = start; r < end; ++r) {
    const float* row = bemb + ((size_t)b * SS + r) * DM + t32 * 8;
    f32x4 v0 = *(const f32x4*)row;
    f32x4 v1 = *(const f32x4*)(row + 4);
#pragma unroll
    for (int j = 0; j < 4; ++j) { a0[j] += v0[j]; a1[j] += v1[j]; }
  }
  float inv = frcp((float)(end - start));
#pragma unroll
  for (int j = 0; j < 4; ++j) { a0[j] *= inv; a1[j] *= inv; }
  *(f32x4*)(pe_out + outbase) = a0;
  *(f32x4*)(pe_out + outbase + 4) = a1;
  if (t32 == 0) plen_out[b * SS + p] = (float)(end - start);
}

// ---------------------------------------------------------------------------
// Launcher — 5 dispatches total
// ---------------------------------------------------------------------------
extern "C" void kernel_launch(void* const* d_in, const int* in_sizes, int n_in,
                              void* d_out, int out_size, void* d_ws, size_t ws_size,
                              hipStream_t stream) {
  const int* bytes = (const int*)d_in[0];
  const float* bemb = (const float*)d_in[1];
  const float* embed_w = (const float*)d_in[2];
  const float* in_proj_w = (const float*)d_in[3];
  const float* conv_w = (const float*)d_in[4];
  const float* conv_b = (const float*)d_in[5];
  const float* x_proj_w = (const float*)d_in[6];
  const float* dt_w = (const float*)d_in[7];
  const float* dt_b = (const float*)d_in[8];
  const float* A_log = (const float*)d_in[9];
  const float* D_param = (const float*)d_in[10];
  const float* out_w = (const float*)d_in[11];
  const float* norm_w = (const float*)d_in[12];
  const float* head_w = (const float*)d_in[13];

  float* out = (float*)d_out;
  float* pe_out = out;                      // (B,S,DM)
  float* plen_out = out + (size_t)TT * DM;  // (B,S)
  float* btp_out = plen_out + TT;           // (B,S)

  char* wsb = (char*)d_ws;
  size_t off = 0;
  auto alloc = [&](size_t bytes_) -> void* {
    void* p = wsb + off;
    off += (bytes_ + 255) & ~(size_t)255;
    return p;
  };
  float* A2 = (float*)alloc((size_t)NLAYERS * DI * DSTATE * 4);
  __hip_bfloat16* xb0 = (__hip_bfloat16*)alloc((size_t)TT * DM * 2);
  __hip_bfloat16* xb1 = (__hip_bfloat16*)alloc((size_t)TT * DM * 2);
  float* ent = (float*)alloc((size_t)TT * 4);
  int* pstart = (int*)alloc((size_t)TT * 4);
  int* npatch = (int*)alloc(256);
  __hip_bfloat16* inWt = (__hip_bfloat16*)alloc((size_t)NLAYERS * 2 * DI * DM * 2);
  __hip_bfloat16* dtWt = (__hip_bfloat16*)alloc((size_t)NLAYERS * DI * DI * 2);
  __hip_bfloat16* oWt = (__hip_bfloat16*)alloc((size_t)NLAYERS * DM * DI * 2);
  __hip_bfloat16* xpWt = (__hip_bfloat16*)alloc((size_t)NLAYERS * 32 * DI * 2);
  __hip_bfloat16* headWt = (__hip_bfloat16*)alloc((size_t)VOCAB * DM * 2);

  // 1: weight transposes (fragment-packed) + A2 + embedding (merged)
  prep_wtrans<<<PW_BLOCKS, 256, 0, stream>>>(
      in_proj_w, inWt, dt_w, dtWt, out_w, oWt, head_w, headWt,
      x_proj_w, xpWt, A_log, A2, bytes, embed_w, xb0);

  // 2: Mamba layer 0 (writes xb1 only)
  size_t fused_lds = (size_t)XBS_BYTES + (size_t)35 * XST * 2 + (size_t)TW * BMST * 4;
  mamba_fused<false><<<TT / TW, 512, fused_lds, stream>>>(
      xb0, xb1,
      (const __bf16*)inWt, (const __bf16*)dtWt, (const __bf16*)oWt,
      (const __bf16*)xpWt,
      conv_w, conv_b, A2, dt_b, D_param, norm_w, nullptr, nullptr);

  // 3: Mamba layer 1 + fused head-GEMM + entropy (writes ent only)
  mamba_fused<true><<<TT / TW, 512, fused_lds, stream>>>(
      xb1, xb0,
      (const __bf16*)(inWt + (size_t)1 * 2 * DI * DM),
      (const __bf16*)(dtWt + (size_t)1 * DI * DI),
      (const __bf16*)(oWt + (size_t)1 * DM * DI),
      (const __bf16*)(xpWt + (size_t)1 * 32 * DI),
      conv_w + (size_t)1 * DI * DCONV, conv_b + (size_t)1 * DI,
      A2 + (size_t)1 * DI * DSTATE, dt_b + (size_t)1 * DI,
      D_param + (size_t)1 * DI, norm_w + (size_t)1 * DM,
      (const __bf16*)headWt, ent);

  // 4: boundary scan (parallel)
  scan_kernel<<<BB, 256, 0, stream>>>(ent, btp_out, pstart, npatch);

  // 5: patch mean pooling (8 patches/block)
  patch_kernel<<<TT / 8, 256, 0, stream>>>(bemb, pstart, npatch, pe_out, plen_out);
}

// Round 16
// 215.462 us; speedup vs baseline: 2.1230x; 1.0359x over previous
//
#include <hip/hip_runtime.h>
#include <hip/hip_bf16.h>
#include <math.h>

// Problem constants
#define BB 8
#define SS 2048
#define TT (BB * SS)      // 16384 tokens
#define DM 256
#define DI 512
#define DSTATE 16
#define DCONV 4
#define NLAYERS 2
#define VOCAB 256
#define LOG_VOCAB 5.545177444479562f
#define RMS_EPS 1.1920929e-07f
#define LOG2E 1.4426950408889634f
#define LN2 0.6931471805599453f
#define THR_ 0.5f

#define TW 32            // tokens per fused block: grid 512 -> 2 blocks/CU
#define XBST 264         // xbs (A-tile) LDS row stride (bf16): 528B -> 2-way aliasing only
#define XST 520          // xcs LDS row stride (bf16 elems): 1040B -> 2-way bank aliasing only
#define BMST 20          // Bms LDS row stride (f32)
#define VST 260          // vst (f32 epilogue overlay) row stride
#define HST3 264         // hts (head A-tile) row stride (bf16)
// LDS layout: xbs [0,25344) | xcs [25344,61744) | Bms [61744,64304)
#define XBS_BYTES 25344
#define VST_OFF 25344
#define HTS_OFF 25344
#define RMSP_OFF 42240
#define RED_OFF 61744

typedef __attribute__((ext_vector_type(8))) __bf16 bf16x8;
typedef __attribute__((ext_vector_type(4))) __bf16 bf16x4;
typedef __attribute__((ext_vector_type(2))) __bf16 bf16x2;
typedef __attribute__((ext_vector_type(4))) float f32x4;

// ---- fast transcendentals (1-ulp class; entropy margin vs THR=0.5 is ~0.4) ----
__device__ __forceinline__ float fexp(float x) { return __builtin_amdgcn_exp2f(x * LOG2E); }
__device__ __forceinline__ float fexp2(float x) { return __builtin_amdgcn_exp2f(x); }
__device__ __forceinline__ float flog(float x) { return __builtin_amdgcn_logf(x) * LN2; }
__device__ __forceinline__ float frcp(float x) { return __builtin_amdgcn_rcpf(x); }
__device__ __forceinline__ float fsigmoid(float x) { return frcp(1.f + fexp(-x)); }
__device__ __forceinline__ float fsoftplus(float x) {
  return fmaxf(x, 0.f) + flog(1.f + fexp(-fabsf(x)));
}

// ---------------------------------------------------------------------------
// Fragment-packed weight layout (round-15 win: 110->76us). The MFMA
// B-fragment for (row-tile R=n/16, k-tile C=k/32) is 64 lanes x 16B; pkidx
// places each fragment as one CONTIGUOUS 1KB block so in-kernel weight
// loads are base + frag*512 + lane*8 (zero address divergence).
// ---------------------------------------------------------------------------
__device__ __forceinline__ size_t pkidx(int n, int k, int K) {
  return ((size_t)(n >> 4) * (K >> 5) + (k >> 5)) * 512 +
         ((((k >> 3) & 3) * 16 + (n & 15)) * 8) + (k & 7);
}

// ---------------------------------------------------------------------------
// prep_wtrans: weight transposes->PACKED (bid<352) + A2 (bid>=352).
// Embedding gather moved INTO layer-0's S-phase (xb0 round-trip deleted:
// -16.8MB read, -8.4MB write in prep, -8.4MB read in layer 0).
// ---------------------------------------------------------------------------
#define WT_BLOCKS 352
#define PW_BLOCKS (WT_BLOCKS + 16)   // +16 blocks for A2 (16384 f32 / 4 / 256)

__global__ __launch_bounds__(256) void prep_wtrans(
    const float* __restrict__ in_proj_w, __hip_bfloat16* __restrict__ inWt,
    const float* __restrict__ dt_w, __hip_bfloat16* __restrict__ dtWt,
    const float* __restrict__ out_w, __hip_bfloat16* __restrict__ oWt,
    const float* __restrict__ head_w, __hip_bfloat16* __restrict__ headWt,
    const float* __restrict__ x_proj_w, __hip_bfloat16* __restrict__ xpWt,
    const float* __restrict__ A_log, float* __restrict__ A2) {
  __shared__ float tile[64][65];
  int bid = blockIdx.x;
  int tid = threadIdx.x;
  if (bid >= WT_BLOCKS) {  // ---- A2 path ----
    int i = (bid - WT_BLOCKS) * 256 + tid;
    f32x4 a = *(const f32x4*)(A_log + i * 4);
    f32x4 o;
#pragma unroll
    for (int j = 0; j < 4; ++j) o[j] = -fexp(a[j]) * LOG2E;
    *(f32x4*)(A2 + i * 4) = o;
    return;
  }
  // ---- wtrans path (transpose f32 [K][N] -> packed bf16 W^T fragments) ----
  const float* src;
  __hip_bfloat16* dst;
  int K, N, kt, nt, nw = 64;
  if (bid < 128) {        // in_proj: [256][1024] -> [1024][256] packed
    int l = bid >> 6, r = bid & 63;
    src = in_proj_w + (size_t)l * 262144; dst = inWt + (size_t)l * 262144;
    K = 256; N = 1024; kt = r >> 4; nt = r & 15;
  } else if (bid < 256) { // dt: [512][512] -> [512][512] packed
    int i = bid - 128; int l = i >> 6, r = i & 63;
    src = dt_w + (size_t)l * 262144; dst = dtWt + (size_t)l * 262144;
    K = 512; N = 512; kt = r >> 3; nt = r & 7;
  } else if (bid < 320) { // out: [512][256] -> [256][512] packed
    int i = bid - 256; int l = i >> 5, r = i & 31;
    src = out_w + (size_t)l * 131072; dst = oWt + (size_t)l * 131072;
    K = 512; N = 256; kt = r >> 2; nt = r & 3;
  } else if (bid < 336) { // head: [256][256] -> [256][256] packed
    int r = bid - 320;
    src = head_w; dst = headWt;
    K = 256; N = 256; kt = r >> 2; nt = r & 3;
  } else {                // x_proj: [512][32] -> [32][512] packed (64x32 tiles)
    int i = bid - 336; int l = i >> 3, r = i & 7;
    src = x_proj_w + (size_t)l * 16384; dst = xpWt + (size_t)l * 16384;
    K = 512; N = 32; kt = r; nt = 0; nw = 32;
  }
  int k0 = kt * 64, n0 = nt * 64;
  if (nw == 64) {
    int r0 = tid >> 4, c4 = (tid & 15) * 4;
#pragma unroll
    for (int rr = 0; rr < 4; ++rr) {
      int r = rr * 16 + r0;
      f32x4 v = *(const f32x4*)(src + (size_t)(k0 + r) * N + n0 + c4);
      tile[r][c4] = v[0]; tile[r][c4 + 1] = v[1]; tile[r][c4 + 2] = v[2]; tile[r][c4 + 3] = v[3];
    }
    __syncthreads();
    int n = tid >> 2, kc = (tid & 3) * 16;
#pragma unroll
    for (int cc = 0; cc < 2; ++cc) {
      int k = kc + cc * 8;
      bf16x8 o;
#pragma unroll
      for (int j = 0; j < 8; ++j) o[j] = (__bf16)tile[k + j][n];
      *(bf16x8*)((__bf16*)dst + pkidx(n0 + n, k0 + k, K)) = o;
    }
  } else {
    int r0 = tid >> 3, c4 = (tid & 7) * 4;
#pragma unroll
    for (int rr = 0; rr < 2; ++rr) {
      int r = rr * 32 + r0;
      f32x4 v = *(const f32x4*)(src + (size_t)(k0 + r) * N + c4);
      tile[r][c4] = v[0]; tile[r][c4 + 1] = v[1]; tile[r][c4 + 2] = v[2]; tile[r][c4 + 3] = v[3];
    }
    __syncthreads();
    int n = tid >> 3, kc = (tid & 7) * 8;
    bf16x8 o;
#pragma unroll
    for (int j = 0; j < 8; ++j) o[j] = (__bf16)tile[kc + j][n];
    *(bf16x8*)((__bf16*)dst + pkidx(n, k0 + kc, K)) = o;
  }
}

// ---------------------------------------------------------------------------
// Fully-fused Mamba layer (round-15 body: fragment-packed weights, 76us).
// Round-16 change: EMBED template — layer 0 stages xbs directly from
// embed_w[bytes[tok]] (f32, L2-hot 256KB table) with the same per-element
// f32->bf16 cast prep used (bit-identical xbs content); xb0 buffer deleted.
// ---------------------------------------------------------------------------
template <bool DOHEAD, bool EMBED>
__global__ __launch_bounds__(512, 4) void mamba_fused(
    const __hip_bfloat16* __restrict__ xbin,  // [TT][256] layer input (bf16; unused if EMBED)
    __hip_bfloat16* __restrict__ xbout,       // [TT][256] layer output (bf16)
    const int* __restrict__ byts,             // [TT] (EMBED only)
    const float* __restrict__ embw,           // [VOCAB][256] f32 (EMBED only)
    const __bf16* __restrict__ inW,           // packed [1024][256]
    const __bf16* __restrict__ dtW,           // packed [512][512]
    const __bf16* __restrict__ oW,            // packed [256][512]
    const __bf16* __restrict__ xpW,           // packed [32][512] (rows 0..15 = B)
    const float* __restrict__ cw, const float* __restrict__ cb,
    const float* __restrict__ A2, const float* __restrict__ dtb,
    const float* __restrict__ Dp, const float* __restrict__ nw,
    const __bf16* __restrict__ hW, float* __restrict__ ent) {
  extern __shared__ char smem[];
  __bf16* xbs = (__bf16*)smem;                       // [48][XBST], live to end
  __bf16* xcs = (__bf16*)(smem + XBS_BYTES);         // [35][XST]: xin -> xc -> y'
  float* Bms = (float*)(smem + XBS_BYTES + 35 * XST * 2);  // [32][BMST]

  int tid = threadIdx.x;
  int lane = tid & 63;
  int w = tid >> 6;          // 8 waves
  int quad = lane >> 4;
  int l15 = lane & 15;
  int t0 = blockIdx.x * TW;
  int s0 = t0 & (SS - 1);

  // ---- S: stage A-tile tokens t0-16..t0+31 -> xbs (48x256, coalesced).
  //      EMBED: gather embed_w[bytes[tok]] (f32) + cast; else read xbin. ----
#pragma unroll
  for (int it = 0; it < 3; ++it) {
    int idx = it * 512 + tid;
    int r = idx >> 5, c8 = (idx & 31) * 8;
    int tok = t0 - 16 + r;
    if (tok < 0) tok = 0;  // only block 0; halo unused there (s0==0)
    if constexpr (EMBED) {
      const float* srcp = embw + (size_t)byts[tok] * DM + c8;
      f32x4 v0 = *(const f32x4*)srcp;
      f32x4 v1 = *(const f32x4*)(srcp + 4);
      bf16x8 ob;
#pragma unroll
      for (int j = 0; j < 4; ++j) { ob[j] = (__bf16)v0[j]; ob[4 + j] = (__bf16)v1[j]; }
      *(bf16x8*)(xbs + r * XBST + c8) = ob;
    } else {
      *(bf16x8*)(xbs + r * XBST + c8) =
          *(const bf16x8*)((const __bf16*)xbin + (size_t)tok * DM + c8);
    }
  }
  __syncthreads();

  // ---- G1: x_in = xbtile @ inW^T cols [w*64,+64), packed B, 2-deep. ----
  int wn64 = w * 64;
#pragma unroll 1
  for (int cth = 0; cth < 2; ++cth) {
    const __bf16* bp[2];
#pragma unroll
    for (int ni = 0; ni < 2; ++ni)
      bp[ni] = inW + (size_t)(w * 4 + cth * 2 + ni) * 8 * 512 + lane * 8;
    f32x4 ga[3][2] = {};
    bf16x8 bnx0[2], bnx1[2];
#pragma unroll
    for (int ni = 0; ni < 2; ++ni) {
      bnx0[ni] = *(const bf16x8*)(bp[ni]);
      bnx1[ni] = *(const bf16x8*)(bp[ni] + 512);
    }
#pragma unroll
    for (int kk = 0; kk < 8; ++kk) {
      int k0 = kk * 32;
      bf16x8 bcur[2];
#pragma unroll
      for (int ni = 0; ni < 2; ++ni) { bcur[ni] = bnx0[ni]; bnx0[ni] = bnx1[ni]; }
      if (kk < 6) {
#pragma unroll
        for (int ni = 0; ni < 2; ++ni)
          bnx1[ni] = *(const bf16x8*)(bp[ni] + (size_t)(kk + 2) * 512);
      }
      bf16x8 af[3];
#pragma unroll
      for (int rt = 0; rt < 3; ++rt)
        af[rt] = *(const bf16x8*)(xbs + (rt * 16 + l15) * XBST + k0 + quad * 8);
#pragma unroll
      for (int rt = 0; rt < 3; ++rt)
#pragma unroll
        for (int ni = 0; ni < 2; ++ni)
          ga[rt][ni] = __builtin_amdgcn_mfma_f32_16x16x32_bf16(af[rt], bcur[ni], ga[rt][ni], 0, 0, 0);
    }
#pragma unroll
    for (int rt = 0; rt < 3; ++rt)
#pragma unroll
      for (int ni = 0; ni < 2; ++ni)
#pragma unroll
        for (int rg = 0; rg < 4; ++rg) {
          int grow = rt * 16 + quad * 4 + rg;
          if (grow >= 13)
            xcs[(grow - 13) * XST + wn64 + cth * 32 + ni * 16 + l15] = (__bf16)ga[rt][ni][rg];
        }
  }
  __syncthreads();  // xin complete in LDS (conv reads all cols)

  // ---- P0: conv+silu IN-PLACE on xcs (halo rows 0..2, tokens rows 3..34) ----
  {
    int d = tid;
    float wv[4];
#pragma unroll
    for (int k = 0; k < 4; ++k) wv[k] = cw[d * 4 + k];
    float b = cb[d];
    float h0 = 0, h1 = 0, h2 = 0;
    if (s0 > 0) {
      h0 = (float)xcs[0 * XST + d];
      h1 = (float)xcs[1 * XST + d];
      h2 = (float)xcs[2 * XST + d];
    }
#pragma unroll 4
    for (int s = 0; s < TW; ++s) {
      float c = (float)xcs[(s + 3) * XST + d];
      float a = b + wv[0] * h0 + wv[1] * h1 + wv[2] * h2 + wv[3] * c;
      xcs[(s + 3) * XST + d] = (__bf16)(a * fsigmoid(a));
      h0 = h1; h1 = h2; h2 = c;
    }
  }
  __syncthreads();

  // ---- P1: Bmat = xc @ xpW^T (waves 0-1; packed xpW rows 0..15 = R0) ----
  if (w < 2) {
    f32x4 bacc = {};
#pragma unroll
    for (int kk = 0; kk < 16; ++kk) {
      bf16x8 a = *(const bf16x8*)(xcs + (w * 16 + l15 + 3) * XST + kk * 32 + quad * 8);
      bf16x8 bb = *(const bf16x8*)(xpW + (size_t)kk * 512 + lane * 8);
      bacc = __builtin_amdgcn_mfma_f32_16x16x32_bf16(a, bb, bacc, 0, 0, 0);
    }
#pragma unroll
    for (int rg = 0; rg < 4; ++rg)
      Bms[(w * 16 + quad * 4 + rg) * BMST + l15] = bacc[rg];
  }

  // ---- P2: dt-GEMM, wave owns channels [w*64,+64). Packed B, 2-deep. ----
  int dbase = w * 64;
  f32x4 acc[2][4] = {};
  {
    const __bf16* dtp[4];
#pragma unroll
    for (int ni = 0; ni < 4; ++ni)
      dtp[ni] = dtW + (size_t)(w * 4 + ni) * 16 * 512 + lane * 8;
    bf16x8 bnx0[4], bnx1[4];
#pragma unroll
    for (int ni = 0; ni < 4; ++ni) {
      bnx0[ni] = *(const bf16x8*)(dtp[ni]);
      bnx1[ni] = *(const bf16x8*)(dtp[ni] + 512);
    }
#pragma unroll
    for (int kk = 0; kk < 16; ++kk) {
      int k0 = kk * 32;
      bf16x8 bcur[4];
#pragma unroll
      for (int ni = 0; ni < 4; ++ni) { bcur[ni] = bnx0[ni]; bnx0[ni] = bnx1[ni]; }
      if (kk < 14) {
#pragma unroll
        for (int ni = 0; ni < 4; ++ni)
          bnx1[ni] = *(const bf16x8*)(dtp[ni] + (size_t)(kk + 2) * 512);
      }
      bf16x8 af[2];
#pragma unroll
      for (int mi = 0; mi < 2; ++mi)
        af[mi] = *(const bf16x8*)(xcs + (mi * 16 + l15 + 3) * XST + k0 + quad * 8);
#pragma unroll
      for (int mi = 0; mi < 2; ++mi)
#pragma unroll
        for (int ni = 0; ni < 4; ++ni)
          acc[mi][ni] = __builtin_amdgcn_mfma_f32_16x16x32_bf16(af[mi], bcur[ni], acc[mi][ni], 0, 0, 0);
    }
  }

  // ---- G2: z = xbtile @ inW^T cols [512+w*64,+64) -> REGISTERS. Packed. ----
  bf16x4 zsave[2][2][2];
#pragma unroll
  for (int cth = 0; cth < 2; ++cth) {
    const __bf16* bp[2];
#pragma unroll
    for (int ni = 0; ni < 2; ++ni)
      bp[ni] = inW + (size_t)(32 + w * 4 + cth * 2 + ni) * 8 * 512 + lane * 8;
    f32x4 gz[2][2] = {};
    bf16x8 bnx0[2], bnx1[2];
#pragma unroll
    for (int ni = 0; ni < 2; ++ni) {
      bnx0[ni] = *(const bf16x8*)(bp[ni]);
      bnx1[ni] = *(const bf16x8*)(bp[ni] + 512);
    }
#pragma unroll
    for (int kk = 0; kk < 8; ++kk) {
      int k0 = kk * 32;
      bf16x8 bcur[2];
#pragma unroll
      for (int ni = 0; ni < 2; ++ni) { bcur[ni] = bnx0[ni]; bnx0[ni] = bnx1[ni]; }
      if (kk < 6) {
#pragma unroll
        for (int ni = 0; ni < 2; ++ni)
          bnx1[ni] = *(const bf16x8*)(bp[ni] + (size_t)(kk + 2) * 512);
      }
      bf16x8 af[2];
#pragma unroll
      for (int rt = 0; rt < 2; ++rt)
        af[rt] = *(const bf16x8*)(xbs + ((16 + rt * 16) + l15) * XBST + k0 + quad * 8);
#pragma unroll
      for (int rt = 0; rt < 2; ++rt)
#pragma unroll
        for (int ni = 0; ni < 2; ++ni)
          gz[rt][ni] = __builtin_amdgcn_mfma_f32_16x16x32_bf16(af[rt], bcur[ni], gz[rt][ni], 0, 0, 0);
    }
#pragma unroll
    for (int rt = 0; rt < 2; ++rt)
#pragma unroll
      for (int ni = 0; ni < 2; ++ni)
#pragma unroll
        for (int rg = 0; rg < 4; ++rg)
          zsave[cth][rt][ni][rg] = (__bf16)gz[rt][ni][rg];
  }
  __syncthreads();  // Bms visible; all full-width xcs reads (P1/P2) done

  // ---- P2b: ssm in-register + fold silu(z) from zsave; write y' to own slab ----
#pragma unroll
  for (int ni = 0; ni < 4; ++ni) {
    int d = dbase + ni * 16 + l15;
    float dtbv = dtb[d];
    float dpv = Dp[d];
    const f32x4* ar = (const f32x4*)(A2 + d * DSTATE);
    f32x4 av[4];
#pragma unroll
    for (int q = 0; q < 4; ++q) av[q] = ar[q];
#pragma unroll
    for (int mi = 0; mi < 2; ++mi) {
#pragma unroll
      for (int rg = 0; rg < 4; ++rg) {
        int tl = mi * 16 + quad * 4 + rg;
        const f32x4* br = (const f32x4*)(Bms + tl * BMST);
        float dt = fsoftplus(acc[mi][ni][rg] + dtbv);
        float s = 0.f;
#pragma unroll
        for (int q = 0; q < 4; ++q) {
          f32x4 bq = br[q];
#pragma unroll
          for (int j = 0; j < 4; ++j) s += fexp2(av[q][j] * dt) * bq[j];
        }
        float xcv = (float)xcs[(tl + 3) * XST + d];
        float y = dt * xcv * s + dpv * xcv;
        float zf = (float)zsave[ni >> 1][mi][ni & 1][rg];
        xcs[(tl + 3) * XST + d] = (__bf16)(y * zf * fsigmoid(zf));
      }
    }
  }
  __syncthreads();  // y' complete block-wide

  // ---- P5: out-GEMM, wave owns cols [w*32,+32). Packed B, 2-deep. ----
  int wn = w * 32;
  f32x4 oacc[2][2] = {};
  {
    const __bf16* op[2];
#pragma unroll
    for (int ni = 0; ni < 2; ++ni)
      op[ni] = oW + (size_t)(w * 2 + ni) * 16 * 512 + lane * 8;
    bf16x8 onx0[2], onx1[2];
#pragma unroll
    for (int ni = 0; ni < 2; ++ni) {
      onx0[ni] = *(const bf16x8*)(op[ni]);
      onx1[ni] = *(const bf16x8*)(op[ni] + 512);
    }
#pragma unroll
    for (int kk = 0; kk < 16; ++kk) {
      int k0 = kk * 32;
      bf16x8 ocur[2];
#pragma unroll
      for (int ni = 0; ni < 2; ++ni) { ocur[ni] = onx0[ni]; onx0[ni] = onx1[ni]; }
      if (kk < 14) {
#pragma unroll
        for (int ni = 0; ni < 2; ++ni)
          onx1[ni] = *(const bf16x8*)(op[ni] + (size_t)(kk + 2) * 512);
      }
      bf16x8 af[2];
#pragma unroll
      for (int mi = 0; mi < 2; ++mi)
        af[mi] = *(const bf16x8*)(xcs + (mi * 16 + l15 + 3) * XST + k0 + quad * 8);
#pragma unroll
      for (int mi = 0; mi < 2; ++mi)
#pragma unroll
        for (int ni = 0; ni < 2; ++ni)
          oacc[mi][ni] = __builtin_amdgcn_mfma_f32_16x16x32_bf16(af[mi], ocur[ni], oacc[mi][ni], 0, 0, 0);
    }
  }
  __syncthreads();  // all xcs reads done; xcs region free for overlays

  if constexpr (!DOHEAD) {
    // ---- P6a: scatter yout into vst (f32 overlay on dead xcs) ----
    float* vst = (float*)(smem + VST_OFF);
#pragma unroll
    for (int mi = 0; mi < 2; ++mi)
#pragma unroll
      for (int ni = 0; ni < 2; ++ni)
#pragma unroll
        for (int rg = 0; rg < 4; ++rg) {
          int tl = mi * 16 + quad * 4 + rg;
          vst[tl * VST + wn + ni * 16 + l15] = oacc[mi][ni][rg];
        }
    __syncthreads();

    // ---- P6b: row-major epilogue: residual (from xbs LDS) + rmsnorm +
    //      FULL-LINE xbout writes. ----
    int row = tid >> 4;       // 0..31
    int seg = tid & 15;
    float vv[4][4];
    float sq = 0.f;
#pragma unroll
    for (int j4 = 0; j4 < 4; ++j4) {
      int c = j4 * 64 + seg * 4;
      bf16x4 rv = *(const bf16x4*)(xbs + (16 + row) * XBST + c);
#pragma unroll
      for (int j = 0; j < 4; ++j) {
        float v = vst[row * VST + c + j] + (float)rv[j];
        vv[j4][j] = v;
        sq += v * v;
      }
    }
    sq += __shfl_xor(sq, 1);
    sq += __shfl_xor(sq, 2);
    sq += __shfl_xor(sq, 4);
    sq += __shfl_xor(sq, 8);
    float r = rsqrtf(sq * (1.f / DM) + RMS_EPS);
    __hip_bfloat16* xbw = xbout + (size_t)(t0 + row) * DM;
#pragma unroll
    for (int j4 = 0; j4 < 4; ++j4) {
      int c = j4 * 64 + seg * 4;
      f32x4 nv = *(const f32x4*)(nw + c);
      bf16x4 ob;
#pragma unroll
      for (int j = 0; j < 4; ++j)
        ob[j] = (__bf16)(vv[j4][j] * r * nv[j]);
      *(bf16x4*)(xbw + c) = ob;
    }
  } else {
    // ---- P6 (DOHEAD): column-partitioned rmsnorm -> LDS hts. ----
    __bf16* hts = (__bf16*)(smem + HTS_OFF);
    float* rmsp = (float*)(smem + RMSP_OFF);   // [32][8]
    float vv[2][2][4];
#pragma unroll
    for (int mi = 0; mi < 2; ++mi) {
#pragma unroll
      for (int rg = 0; rg < 4; ++rg) {
        int tl = mi * 16 + quad * 4 + rg;
        float sqp = 0.f;
#pragma unroll
        for (int ni = 0; ni < 2; ++ni) {
          float rv = (float)xbs[(16 + tl) * XBST + wn + ni * 16 + l15];
          float v = oacc[mi][ni][rg] + rv;
          vv[mi][ni][rg] = v;
          sqp += v * v;
        }
        sqp += __shfl_xor(sqp, 1);
        sqp += __shfl_xor(sqp, 2);
        sqp += __shfl_xor(sqp, 4);
        sqp += __shfl_xor(sqp, 8);
        if (l15 == 0) rmsp[tl * 8 + w] = sqp;
      }
    }
    __syncthreads();
#pragma unroll
    for (int mi = 0; mi < 2; ++mi) {
#pragma unroll
      for (int rg = 0; rg < 4; ++rg) {
        int tl = mi * 16 + quad * 4 + rg;
        float tot = 0.f;
#pragma unroll
        for (int ww = 0; ww < 8; ++ww) tot += rmsp[tl * 8 + ww];
        float r = rsqrtf(tot * (1.f / DM) + RMS_EPS);
#pragma unroll
        for (int ni = 0; ni < 2; ++ni) {
          int c = wn + ni * 16 + l15;
          hts[tl * HST3 + c] = (__bf16)(vv[mi][ni][rg] * r * nw[c]);
        }
      }
    }
    __syncthreads();

    // ---- H: fused head-GEMM + entropy. Packed hW (KC=8). ----
    float* red = (float*)(smem + RED_OFF);  // [32][8][2], reuses dead Bms
    int wv = w * 32;
    f32x4 hacc[2][2] = {};
#pragma unroll
    for (int kk = 0; kk < 8; ++kk) {
      int k0 = kk * 32;
      bf16x8 b0 = *(const bf16x8*)(hW + ((size_t)(w * 2) * 8 + kk) * 512 + lane * 8);
      bf16x8 b1 = *(const bf16x8*)(hW + ((size_t)(w * 2 + 1) * 8 + kk) * 512 + lane * 8);
      bf16x8 a0 = *(const bf16x8*)(hts + l15 * HST3 + k0 + quad * 8);
      bf16x8 a1 = *(const bf16x8*)(hts + (16 + l15) * HST3 + k0 + quad * 8);
      hacc[0][0] = __builtin_amdgcn_mfma_f32_16x16x32_bf16(a0, b0, hacc[0][0], 0, 0, 0);
      hacc[0][1] = __builtin_amdgcn_mfma_f32_16x16x32_bf16(a0, b1, hacc[0][1], 0, 0, 0);
      hacc[1][0] = __builtin_amdgcn_mfma_f32_16x16x32_bf16(a1, b0, hacc[1][0], 0, 0, 0);
      hacc[1][1] = __builtin_amdgcn_mfma_f32_16x16x32_bf16(a1, b1, hacc[1][1], 0, 0, 0);
    }
#pragma unroll
    for (int mi = 0; mi < 2; ++mi) {
#pragma unroll
      for (int rg = 0; rg < 4; ++rg) {
        float l0 = hacc[mi][0][rg], l1 = hacc[mi][1][rg];
        float e0 = fexp(l0), e1 = fexp(l1);
        float s = e0 + e1;
        float u = e0 * l0 + e1 * l1;
        s += __shfl_xor(s, 1); u += __shfl_xor(u, 1);
        s += __shfl_xor(s, 2); u += __shfl_xor(u, 2);
        s += __shfl_xor(s, 4); u += __shfl_xor(u, 4);
        s += __shfl_xor(s, 8); u += __shfl_xor(u, 8);
        if (l15 == 0) {
          int tl = mi * 16 + quad * 4 + rg;
          red[(tl * 8 + w) * 2] = s;
          red[(tl * 8 + w) * 2 + 1] = u;
        }
      }
    }
    __syncthreads();
    if (tid < 32) {
      float s = 0.f, u = 0.f;
#pragma unroll
      for (int ww = 0; ww < 8; ++ww) {
        s += red[(tid * 8 + ww) * 2];
        u += red[(tid * 8 + ww) * 2 + 1];
      }
      ent[t0 + tid] = (flog(s) - u * frcp(s)) * (1.f / LOG_VOCAB);
    }
  }
}

// ---------------------------------------------------------------------------
// Parallel boundary scan (anchors via block max-scan). BB blocks x 256 thr.
// ---------------------------------------------------------------------------
__global__ __launch_bounds__(256) void scan_kernel(
    const float* __restrict__ ent, float* __restrict__ btp_out,
    int* __restrict__ pstart, int* __restrict__ npatch) {
  __shared__ int sh[256];
  int b = blockIdx.x, t = threadIdx.x;
  int sbase = t * 8;
  f32x4 e0 = *(const f32x4*)(ent + (size_t)b * SS + sbase);
  f32x4 e1 = *(const f32x4*)(ent + (size_t)b * SS + sbase + 4);
  float e[8] = {e0[0], e0[1], e0[2], e0[3], e1[0], e1[1], e1[2], e1[3]};
  int la = -1;
  unsigned cbits = 0;
#pragma unroll
  for (int j = 0; j < 8; ++j) {
    int s = sbase + j;
    bool cb = (s == 0) || (e[j] > THR_);
    if (cb) { la = s; cbits |= 1u << j; }
  }
  sh[t] = la;
  __syncthreads();
  int run = la;
  for (int off = 1; off < 256; off <<= 1) {
    int other = (t >= off) ? sh[t - off] : -1;
    __syncthreads();
    run = max(run, other);
    sh[t] = run;
    __syncthreads();
  }
  int anchor = (t > 0) ? sh[t - 1] : -1;
  unsigned bits = 0;
#pragma unroll
  for (int j = 0; j < 8; ++j) {
    int s = sbase + j;
    bool cb = (cbits >> j) & 1u;
    bool bnd;
    if (cb) { bnd = true; anchor = s; }
    else bnd = ((s - anchor) & 7) == 0;
    bits |= (unsigned)bnd << j;
  }
  int cnt = __popc(bits);
  __syncthreads();
  sh[t] = cnt;
  __syncthreads();
  int runc = cnt;
  for (int off = 1; off < 256; off <<= 1) {
    int other = (t >= off) ? sh[t - off] : 0;
    __syncthreads();
    runc += other;
    sh[t] = runc;
    __syncthreads();
  }
  if (t == 255) npatch[b] = runc;
  int btp = (runc - cnt) - 1;
#pragma unroll
  for (int j = 0; j < 8; ++j) {
    int s = sbase + j;
    if ((bits >> j) & 1u) { ++btp; pstart[b * SS + btp] = s; }
    btp_out[b * SS + s] = (float)btp;
  }
}

// ---------------------------------------------------------------------------
// patch mean pooling: 2048 blocks, 8 patches/block, 32 threads/patch.
// ---------------------------------------------------------------------------
__global__ __launch_bounds__(256) void patch_kernel(
    const float* __restrict__ bemb, const int* __restrict__ pstart,
    const int* __restrict__ npatch, float* __restrict__ pe_out,
    float* __restrict__ plen_out) {
  int bp8 = blockIdx.x;            // 0..2047
  int b = bp8 >> 8;                // 256 blocks per batch
  int p0 = (bp8 & 255) * 8;
  int t = threadIdx.x;
  int g = t >> 5;                  // patch group 0..7
  int t32 = t & 31;
  int p = p0 + g;
  int np = npatch[b];
  size_t outbase = ((size_t)b * SS + p) * DM + t32 * 8;
  if (p >= np) {
    f32x4 z = {0.f, 0.f, 0.f, 0.f};
    *(f32x4*)(pe_out + outbase) = z;
    *(f32x4*)(pe_out + outbase + 4) = z;
    if (t32 == 0) plen_out[b * SS + p] = 0.f;
    return;
  }
  int start = pstart[b * SS + p];
  int end = (p + 1 < np) ? pstart[b * SS + p + 1] : SS;
  f32x4 a0 = {0.f, 0.f, 0.f, 0.f}, a1 = {0.f, 0.f, 0.f, 0.f};
  for (int r = start; r < end; ++r) {
    const float* row = bemb + ((size_t)b * SS + r) * DM + t32 * 8;
    f32x4 v0 = *(const f32x4*)row;
    f32x4 v1 = *(const f32x4*)(row + 4);
#pragma unroll
    for (int j = 0; j < 4; ++j) { a0[j] += v0[j]; a1[j] += v1[j]; }
  }
  float inv = frcp((float)(end - start));
#pragma unroll
  for (int j = 0; j < 4; ++j) { a0[j] *= inv; a1[j] *= inv; }
  *(f32x4*)(pe_out + outbase) = a0;
  *(f32x4*)(pe_out + outbase + 4) = a1;
  if (t32 == 0) plen_out[b * SS + p] = (float)(end - start);
}

// ---------------------------------------------------------------------------
// Launcher — 5 dispatches total
// ---------------------------------------------------------------------------
extern "C" void kernel_launch(void* const* d_in, const int* in_sizes, int n_in,
                              void* d_out, int out_size, void* d_ws, size_t ws_size,
                              hipStream_t stream) {
  const int* bytes = (const int*)d_in[0];
  const float* bemb = (const float*)d_in[1];
  const float* embed_w = (const float*)d_in[2];
  const float* in_proj_w = (const float*)d_in[3];
  const float* conv_w = (const float*)d_in[4];
  const float* conv_b = (const float*)d_in[5];
  const float* x_proj_w = (const float*)d_in[6];
  const float* dt_w = (const float*)d_in[7];
  const float* dt_b = (const float*)d_in[8];
  const float* A_log = (const float*)d_in[9];
  const float* D_param = (const float*)d_in[10];
  const float* out_w = (const float*)d_in[11];
  const float* norm_w = (const float*)d_in[12];
  const float* head_w = (const float*)d_in[13];

  float* out = (float*)d_out;
  float* pe_out = out;                      // (B,S,DM)
  float* plen_out = out + (size_t)TT * DM;  // (B,S)
  float* btp_out = plen_out + TT;           // (B,S)

  char* wsb = (char*)d_ws;
  size_t off = 0;
  auto alloc = [&](size_t bytes_) -> void* {
    void* p = wsb + off;
    off += (bytes_ + 255) & ~(size_t)255;
    return p;
  };
  float* A2 = (float*)alloc((size_t)NLAYERS * DI * DSTATE * 4);
  __hip_bfloat16* xb1 = (__hip_bfloat16*)alloc((size_t)TT * DM * 2);
  float* ent = (float*)alloc((size_t)TT * 4);
  int* pstart = (int*)alloc((size_t)TT * 4);
  int* npatch = (int*)alloc(256);
  __hip_bfloat16* inWt = (__hip_bfloat16*)alloc((size_t)NLAYERS * 2 * DI * DM * 2);
  __hip_bfloat16* dtWt = (__hip_bfloat16*)alloc((size_t)NLAYERS * DI * DI * 2);
  __hip_bfloat16* oWt = (__hip_bfloat16*)alloc((size_t)NLAYERS * DM * DI * 2);
  __hip_bfloat16* xpWt = (__hip_bfloat16*)alloc((size_t)NLAYERS * 32 * DI * 2);
  __hip_bfloat16* headWt = (__hip_bfloat16*)alloc((size_t)VOCAB * DM * 2);

  // 1: weight transposes (fragment-packed) + A2 (embedding moved into layer 0)
  prep_wtrans<<<PW_BLOCKS, 256, 0, stream>>>(
      in_proj_w, inWt, dt_w, dtWt, out_w, oWt, head_w, headWt,
      x_proj_w, xpWt, A_log, A2);

  // 2: Mamba layer 0 (EMBED: gathers embed_w[bytes] in S-phase; writes xb1)
  size_t fused_lds = (size_t)XBS_BYTES + (size_t)35 * XST * 2 + (size_t)TW * BMST * 4;
  mamba_fused<false, true><<<TT / TW, 512, fused_lds, stream>>>(
      nullptr, xb1, bytes, embed_w,
      (const __bf16*)inWt, (const __bf16*)dtWt, (const __bf16*)oWt,
      (const __bf16*)xpWt,
      conv_w, conv_b, A2, dt_b, D_param, norm_w, nullptr, nullptr);

  // 3: Mamba layer 1 + fused head-GEMM + entropy (writes ent only)
  mamba_fused<true, false><<<TT / TW, 512, fused_lds, stream>>>(
      xb1, nullptr, nullptr, nullptr,
      (const __bf16*)(inWt + (size_t)1 * 2 * DI * DM),
      (const __bf16*)(dtWt + (size_t)1 * DI * DI),
      (const __bf16*)(oWt + (size_t)1 * DM * DI),
      (const __bf16*)(xpWt + (size_t)1 * 32 * DI),
      conv_w + (size_t)1 * DI * DCONV, conv_b + (size_t)1 * DI,
      A2 + (size_t)1 * DI * DSTATE, dt_b + (size_t)1 * DI,
      D_param + (size_t)1 * DI, norm_w + (size_t)1 * DM,
      (const __bf16*)headWt, ent);

  // 4: boundary scan (parallel)
  scan_kernel<<<BB, 256, 0, stream>>>(ent, btp_out, pstart, npatch);

  // 5: patch mean pooling (8 patches/block)
  patch_kernel<<<TT / 8, 256, 0, stream>>>(bemb, pstart, npatch, pe_out, plen_out);
}